// Round 3
// baseline (462.278 us; speedup 1.0000x reference)
//
#include <hip/hip_runtime.h>
#include <hip/hip_bf16.h>

#define Bsz 4
#define Ssz 1024
#define Dsz 768
#define Hn 12
#define DKsz 64
#define NUMEMB 10

// d_ws layout (bytes)
#define POSF_OFF 64
#define EMBF_OFF 32832          // 64 + 8192*4
#define K_OFF    35392          // EMBF_OFF + 640*4, 64-aligned
#define V_OFF    6326848        // K_OFF + 4*1024*768*2

typedef __attribute__((ext_vector_type(8))) short short8;
typedef __attribute__((ext_vector_type(8))) float float8;
typedef __attribute__((ext_vector_type(4))) float f32x4;

__device__ __forceinline__ float bfbits2f(short u) {
    union { unsigned int i; float f; } v;
    v.i = ((unsigned int)(unsigned short)u) << 16;
    return v.f;
}
__device__ __forceinline__ unsigned short f2bf_bits(float f) {
    __hip_bfloat16 h = __float2bfloat16(f);
    return *reinterpret_cast<unsigned short*>(&h);
}

// dtype-dispatched loads: elemIdx is an ELEMENT index (same for both dtypes)
template<bool BF16>
__device__ __forceinline__ float loadf(const void* base, size_t idx) {
    if constexpr (BF16) return __bfloat162float(((const __hip_bfloat16*)base)[idx]);
    else return ((const float*)base)[idx];
}
template<bool BF16>
__device__ __forceinline__ short8 load8bf(const void* base, size_t idx) {
    if constexpr (BF16) {
        return *(const short8*)((const short*)base + idx);
    } else {
        float8 f = *(const float8*)((const float*)base + idx);
        short8 r;
#pragma unroll
        for (int i = 0; i < 8; i++) r[i] = (short)f2bf_bits(f[i]);
        return r;
    }
}

// ---------------- dtype detector ------------------------------------------
// For each tensor: read n 32-bit words; the low half-word's bits [14:7] are a
// bf16 exponent if data is bf16 (concentrated in [110,145] for all our value
// ranges: N(0,1), U(0,1e5), xavier ~0.09), but random mantissa bits if data is
// fp32 (~14% in-window). flags[which] = 1 iff bf16.
__global__ __launch_bounds__(64) void detect_kernel(
    const unsigned int* __restrict__ q, const unsigned int* __restrict__ p,
    const unsigned int* __restrict__ w, const unsigned int* __restrict__ e,
    int* __restrict__ flags)
{
    const int which = blockIdx.x;
    const unsigned int* ptr = (which == 0) ? q : ((which == 1) ? p : ((which == 2) ? w : e));
    const int n = (which == 3) ? 320 : ((which == 1) ? 4096 : 1024);
    int cnt = 0;
    for (int i = threadIdx.x; i < n; i += 64) {
        const unsigned int ex = (ptr[i] >> 7) & 0xFF;
        cnt += (ex >= 110 && ex <= 145) ? 1 : 0;
    }
#pragma unroll
    for (int off = 1; off < 64; off <<= 1) cnt += __shfl_xor(cnt, off, 64);
    if (threadIdx.x == 0) flags[which] = (2 * cnt > n) ? 1 : 0;
}

// canonicalize pos and emb to fp32 scratch (exact conversion either way)
__global__ __launch_bounds__(256) void prep_kernel(
    const void* __restrict__ pos, const void* __restrict__ emb,
    const int* __restrict__ flags, float* __restrict__ posf, float* __restrict__ embf)
{
    const bool pb = flags[1] != 0, eb = flags[3] != 0;
    for (int i = threadIdx.x; i < Bsz * Ssz * 2; i += 256)
        posf[i] = pb ? loadf<true>(pos, i) : loadf<false>(pos, i);
    for (int i = threadIdx.x; i < NUMEMB * DKsz; i += 256)
        embf[i] = eb ? loadf<true>(emb, i) : loadf<false>(emb, i);
}

// ---------------- Projection GEMM: Y = X @ W^T + b -------------------------
template<bool XB, bool WB>
__device__ __forceinline__ void proj_body(
    const void* X, const void* W, const void* bias, void* Y, bool ybf,
    int bx, int by)
{
    const int tid  = threadIdx.x;
    const int wave = tid >> 6;
    const int lane = tid & 63;
    const int l15  = lane & 15;
    const int quad = lane >> 4;

    const int m0 = bx * 64 + (wave & 1) * 32;
    const int n0 = by * 128 + (wave >> 1) * 64;

    f32x4 acc[2][4];
#pragma unroll
    for (int i = 0; i < 2; i++)
#pragma unroll
        for (int j = 0; j < 4; j++) acc[i][j] = (f32x4)0.0f;

    for (int kk = 0; kk < Dsz; kk += 32) {
        const int kofs = kk + quad * 8;
        short8 a0 = load8bf<XB>(X, (size_t)(m0 + l15) * Dsz + kofs);
        short8 a1 = load8bf<XB>(X, (size_t)(m0 + 16 + l15) * Dsz + kofs);
#pragma unroll
        for (int j = 0; j < 4; j++) {
            short8 bfr = load8bf<WB>(W, (size_t)(n0 + j * 16 + l15) * Dsz + kofs);
            acc[0][j] = __builtin_amdgcn_mfma_f32_16x16x32_bf16(a0, bfr, acc[0][j], 0, 0, 0);
            acc[1][j] = __builtin_amdgcn_mfma_f32_16x16x32_bf16(a1, bfr, acc[1][j], 0, 0, 0);
        }
    }

#pragma unroll
    for (int i = 0; i < 2; i++) {
#pragma unroll
        for (int j = 0; j < 4; j++) {
            const int n = n0 + j * 16 + l15;
            const float bv_ = loadf<WB>(bias, n);   // biases are zeros; dtype-proof anyway
#pragma unroll
            for (int r = 0; r < 4; r++) {
                const int m = m0 + i * 16 + quad * 4 + r;
                const float val = acc[i][j][r] + bv_;
                if (ybf) ((__hip_bfloat16*)Y)[(size_t)m * Dsz + n] = __float2bfloat16(val);
                else     ((float*)Y)[(size_t)m * Dsz + n] = val;
            }
        }
    }
}

__global__ __launch_bounds__(256) void proj_kernel(
    const void* X0, const void* X1, const void* X2,
    const void* Wq, const void* bq, const void* Wk, const void* bk,
    const void* Wv, const void* bv,
    void* Qw, void* Kw, void* Vw, const int* __restrict__ flags)
{
    const int z = blockIdx.z;
    const void* X = (z == 0) ? X0 : ((z == 1) ? X1 : X2);
    const void* W = (z == 0) ? Wq : ((z == 1) ? Wk : Wv);
    const void* B = (z == 0) ? bq : ((z == 1) ? bk : bv);
    void* Y = (z == 0) ? Qw : ((z == 1) ? Kw : Vw);
    const bool xb = flags[0] != 0, wb = flags[2] != 0;
    // K/V always stored bf16 in ws; Q stored in the input (=output) dtype.
    const bool ybf = xb || (z != 0);
    if (xb) { if (wb) proj_body<true , true >(X, W, B, Y, ybf, blockIdx.x, blockIdx.y);
              else    proj_body<true , false>(X, W, B, Y, ybf, blockIdx.x, blockIdx.y); }
    else    { if (wb) proj_body<false, true >(X, W, B, Y, ybf, blockIdx.x, blockIdx.y);
              else    proj_body<false, false>(X, W, B, Y, ybf, blockIdx.x, blockIdx.y); }
}

// ---------------- Flash attention with distance-aware key bias --------------
template<bool QB>
__device__ __forceinline__ void attn_body(
    const void* Qw, const short* __restrict__ Ks, const short* __restrict__ Vs,
    const float* __restrict__ posf, const float* __restrict__ embf, void* out,
    unsigned short* Klds, unsigned short* Vtlds, unsigned short* Plds,
    float* qe, float* qpos, float* kpos)
{
    const int qt = blockIdx.x, h = blockIdx.y, b = blockIdx.z;
    const int tid  = threadIdx.x;
    const int wave = tid >> 6;
    const int lane = tid & 63;
    const int l15  = lane & 15;
    const int quad = lane >> 4;

    // stage q positions (fp32 canonical, exact)
    if (tid < 128) {
        const int row = tid >> 1, c = tid & 1;
        qpos[tid] = posf[((size_t)b * Ssz + qt * 64 + row) * 2 + c];
    }
    // qe[row][e] = sum_d Q[b, qrow, h*64+d] * emb[e][d]
    for (int p = tid; p < 64 * NUMEMB; p += 256) {
        const int row = p / NUMEMB, e = p - row * NUMEMB;
        const size_t qoff = ((size_t)b * Ssz + qt * 64 + row) * Dsz + h * DKsz;
        float s = 0.f;
#pragma unroll
        for (int c = 0; c < 8; c++) {
            short8 qv = load8bf<QB>(Qw, qoff + c * 8);
            const float* er = embf + e * DKsz + c * 8;
#pragma unroll
            for (int i = 0; i < 8; i++) s += bfbits2f(qv[i]) * er[i];
        }
        qe[p] = s;
    }

    // Q fragments (A-layout): row = l15, k = quad*8 + j
    short8 qfrag[2];
    {
        const size_t qbase = ((size_t)b * Ssz + qt * 64 + wave * 16 + l15) * Dsz + h * DKsz;
        qfrag[0] = load8bf<QB>(Qw, qbase + quad * 8);
        qfrag[1] = load8bf<QB>(Qw, qbase + 32 + quad * 8);
    }

    float m_run[4], l_run[4];
    f32x4 oacc[4];
#pragma unroll
    for (int r = 0; r < 4; r++) { m_run[r] = -1e30f; l_run[r] = 0.f; }
#pragma unroll
    for (int j = 0; j < 4; j++) oacc[j] = (f32x4)0.0f;

    const float MAXD = 141421.35623730951f;  // fp32(100000*sqrt(2))
    const float NINE = 9.0f;

    for (int it = 0; it < 16; it++) {
        __syncthreads();  // LDS reuse + first-iter qe/qpos visibility
        {
            int t = tid;
#pragma unroll
            for (int rep = 0; rep < 2; rep++, t += 256) {
                const int row = t >> 3, chunk = t & 7;
                short8 v = *(const short8*)(Ks + ((size_t)b * Ssz + it * 64 + row) * Dsz + h * DKsz + chunk * 8);
                *(short8*)&Klds[row * 72 + chunk * 8] = v;
            }
        }
        {
            int t = tid;
#pragma unroll
            for (int rep = 0; rep < 2; rep++, t += 256) {
                const int s = t >> 3, chunk = t & 7;
                short8 v = *(const short8*)(Vs + ((size_t)b * Ssz + it * 64 + s) * Dsz + h * DKsz + chunk * 8);
#pragma unroll
                for (int i = 0; i < 8; i++)
                    Vtlds[(chunk * 8 + i) * 72 + s] = (unsigned short)v[i];
            }
        }
        if (tid < 128) {
            const int row = tid >> 1, c = tid & 1;
            kpos[tid] = posf[((size_t)b * Ssz + it * 64 + row) * 2 + c];
        }
        __syncthreads();

        // S = Q K^T via MFMA
        f32x4 sf[4];
#pragma unroll
        for (int j = 0; j < 4; j++) sf[j] = (f32x4)0.0f;
#pragma unroll
        for (int st = 0; st < 2; st++) {
#pragma unroll
            for (int j = 0; j < 4; j++) {
                short8 kb = *(const short8*)&Klds[(j * 16 + l15) * 72 + st * 32 + quad * 8];
                sf[j] = __builtin_amdgcn_mfma_f32_16x16x32_bf16(qfrag[st], kb, sf[j], 0, 0, 0);
            }
        }

        // bias + scale. idx math matches np fp32 sequence exactly: no FMA.
        float sv[4][4];
#pragma unroll
        for (int r = 0; r < 4; r++) {
            const int m = wave * 16 + quad * 4 + r;
            const float qx = qpos[m * 2], qy = qpos[m * 2 + 1];
#pragma unroll
            for (int j = 0; j < 4; j++) {
                const int n = j * 16 + l15;
                const float dx = __fsub_rn(qx, kpos[n * 2]);
                const float dy = __fsub_rn(qy, kpos[n * 2 + 1]);
                const float ss = __fadd_rn(__fmul_rn(dx, dx), __fmul_rn(dy, dy));
                const float dist = __fdiv_rn(sqrtf(ss), MAXD);
                const float d9 = __fmul_rn(dist, NINE);
                int idx = (int)rintf(d9);
                idx = idx < 0 ? 0 : (idx > NUMEMB - 1 ? NUMEMB - 1 : idx);
                sv[r][j] = (sf[j][r] + qe[m * NUMEMB + idx]) * 0.125f;
            }
        }

        // online softmax per row (rows replicated across 16 lanes of a quad)
        float alpha[4];
#pragma unroll
        for (int r = 0; r < 4; r++) {
            float vmax = sv[r][0];
#pragma unroll
            for (int j = 1; j < 4; j++) vmax = fmaxf(vmax, sv[r][j]);
#pragma unroll
            for (int off = 1; off < 16; off <<= 1) vmax = fmaxf(vmax, __shfl_xor(vmax, off, 16));
            const float mnew = fmaxf(m_run[r], vmax);
            alpha[r] = __expf(m_run[r] - mnew);
            m_run[r] = mnew;
            float psum = 0.f;
#pragma unroll
            for (int j = 0; j < 4; j++) {
                const float p = __expf(sv[r][j] - mnew);
                sv[r][j] = p;
                psum += p;
            }
#pragma unroll
            for (int off = 1; off < 16; off <<= 1) psum += __shfl_xor(psum, off, 16);
            l_run[r] = l_run[r] * alpha[r] + psum;
        }
#pragma unroll
        for (int j = 0; j < 4; j++) {
            f32x4 o = oacc[j];
#pragma unroll
            for (int r = 0; r < 4; r++) o[r] *= alpha[r];
            oacc[j] = o;
        }

        // P (bf16) -> LDS in A-layout positions; wave-private rows
#pragma unroll
        for (int r = 0; r < 4; r++) {
            const int m = wave * 16 + quad * 4 + r;
#pragma unroll
            for (int j = 0; j < 4; j++) {
                Plds[m * 72 + j * 16 + l15] = f2bf_bits(sv[r][j]);
            }
        }
        __syncthreads();   // conservative: ensure P fully visible before PV

        // O += P @ V via MFMA
#pragma unroll
        for (int st = 0; st < 2; st++) {
            short8 pf = *(const short8*)&Plds[(wave * 16 + l15) * 72 + st * 32 + quad * 8];
#pragma unroll
            for (int j = 0; j < 4; j++) {
                short8 vb = *(const short8*)&Vtlds[(j * 16 + l15) * 72 + st * 32 + quad * 8];
                oacc[j] = __builtin_amdgcn_mfma_f32_16x16x32_bf16(pf, vb, oacc[j], 0, 0, 0);
            }
        }
    }

    __syncthreads();  // all Q reads of this block's region done before overwrite

#pragma unroll
    for (int r = 0; r < 4; r++) {
        const float inv = 1.0f / l_run[r];
        const int m = qt * 64 + wave * 16 + quad * 4 + r;
#pragma unroll
        for (int j = 0; j < 4; j++) {
            const int n = h * DKsz + j * 16 + l15;
            const float val = oacc[j][r] * inv;
            const size_t oidx = ((size_t)b * Ssz + m) * Dsz + n;
            if constexpr (QB) ((__hip_bfloat16*)out)[oidx] = __float2bfloat16(val);
            else              ((float*)out)[oidx] = val;
        }
    }
}

__global__ __launch_bounds__(256) void attn_kernel(
    const void* Qw, const short* __restrict__ Ks, const short* __restrict__ Vs,
    const float* __restrict__ posf, const float* __restrict__ embf, void* out,
    const int* __restrict__ flags)
{
    __shared__ __align__(16) unsigned short Klds[64 * 72];
    __shared__ __align__(16) unsigned short Vtlds[64 * 72];
    __shared__ __align__(16) unsigned short Plds[64 * 72];
    __shared__ __align__(16) float qe[64 * NUMEMB];
    __shared__ __align__(16) float qpos[64 * 2];
    __shared__ __align__(16) float kpos[64 * 2];

    if (flags[0] != 0)
        attn_body<true >(Qw, Ks, Vs, posf, embf, out, Klds, Vtlds, Plds, qe, qpos, kpos);
    else
        attn_body<false>(Qw, Ks, Vs, posf, embf, out, Klds, Vtlds, Plds, qe, qpos, kpos);
}

extern "C" void kernel_launch(void* const* d_in, const int* in_sizes, int n_in,
                              void* d_out, int out_size, void* d_ws, size_t ws_size,
                              hipStream_t stream) {
    const void* query = d_in[0];
    const void* key   = d_in[1];
    const void* value = d_in[2];
    const void* tpos  = d_in[3];
    const void* Wq    = d_in[4];
    const void* bq    = d_in[5];
    const void* Wk    = d_in[6];
    const void* bk    = d_in[7];
    const void* Wv    = d_in[8];
    const void* bv    = d_in[9];
    const void* emb   = d_in[10];

    int*   flags = (int*)d_ws;
    float* posf  = (float*)((char*)d_ws + POSF_OFF);
    float* embf  = (float*)((char*)d_ws + EMBF_OFF);
    void*  Kw    = (char*)d_ws + K_OFF;
    void*  Vw    = (char*)d_ws + V_OFF;
    void*  Qw    = d_out;   // Q staged in d_out (each attn block reads then
                            // overwrites only its own (b,row-tile,head) region)

    detect_kernel<<<4, 64, 0, stream>>>(
        (const unsigned int*)query, (const unsigned int*)tpos,
        (const unsigned int*)Wq, (const unsigned int*)emb, flags);

    prep_kernel<<<1, 256, 0, stream>>>(tpos, emb, flags, posf, embf);

    proj_kernel<<<dim3(64, 6, 3), 256, 0, stream>>>(
        query, key, value, Wq, bq, Wk, bk, Wv, bv, Qw, Kw, Vw, flags);

    attn_kernel<<<dim3(16, Hn, Bsz), 256, 0, stream>>>(
        Qw, (const short*)Kw, (const short*)Vw, posf, embf, d_out, flags);
}

// Round 4
// 289.273 us; speedup vs baseline: 1.5981x; 1.5981x over previous
//
#include <hip/hip_runtime.h>
#include <hip/hip_bf16.h>

#define Bsz 4
#define Ssz 1024
#define Dsz 768
#define Hn 12
#define DKsz 64
#define NUMEMB 10

// d_ws layout (bytes)
#define POSF_OFF 64
#define EMBF_OFF 32832          // 64 + 8192*4
#define K_OFF    35392          // EMBF_OFF + 640*4, 64-aligned
#define V_OFF    6326848        // K_OFF + 4*1024*768*2

// proj GEMM tile config
#define BM 128
#define BN 128
#define BK 32
#define LPAD 40                 // LDS row stride (elems): 32 + 8 pad → 2-way banks

typedef __attribute__((ext_vector_type(8))) short short8;
typedef __attribute__((ext_vector_type(8))) float float8;
typedef __attribute__((ext_vector_type(4))) float f32x4;

__device__ __forceinline__ float bfbits2f(short u) {
    union { unsigned int i; float f; } v;
    v.i = ((unsigned int)(unsigned short)u) << 16;
    return v.f;
}
__device__ __forceinline__ unsigned short f2bf_bits(float f) {
    __hip_bfloat16 h = __float2bfloat16(f);
    return *reinterpret_cast<unsigned short*>(&h);
}

// dtype-dispatched loads: idx is an ELEMENT index (same for both dtypes)
template<bool BF16>
__device__ __forceinline__ float loadf(const void* base, size_t idx) {
    if constexpr (BF16) return __bfloat162float(((const __hip_bfloat16*)base)[idx]);
    else return ((const float*)base)[idx];
}
template<bool BF16>
__device__ __forceinline__ short8 load8bf(const void* base, size_t idx) {
    if constexpr (BF16) {
        return *(const short8*)((const short*)base + idx);
    } else {
        float8 f = *(const float8*)((const float*)base + idx);
        short8 r;
#pragma unroll
        for (int i = 0; i < 8; i++) r[i] = (short)f2bf_bits(f[i]);
        return r;
    }
}

// ---------------- dtype detector ------------------------------------------
// Low half-word bits [14:7] are a bf16 exponent if data is bf16 (concentrated
// in [110,145]); random mantissa bits if fp32 (~14% in-window).
__global__ __launch_bounds__(64) void detect_kernel(
    const unsigned int* __restrict__ q, const unsigned int* __restrict__ p,
    const unsigned int* __restrict__ w, const unsigned int* __restrict__ e,
    int* __restrict__ flags)
{
    const int which = blockIdx.x;
    const unsigned int* ptr = (which == 0) ? q : ((which == 1) ? p : ((which == 2) ? w : e));
    const int n = (which == 3) ? 320 : ((which == 1) ? 4096 : 1024);
    int cnt = 0;
    for (int i = threadIdx.x; i < n; i += 64) {
        const unsigned int ex = (ptr[i] >> 7) & 0xFF;
        cnt += (ex >= 110 && ex <= 145) ? 1 : 0;
    }
#pragma unroll
    for (int off = 1; off < 64; off <<= 1) cnt += __shfl_xor(cnt, off, 64);
    if (threadIdx.x == 0) flags[which] = (2 * cnt > n) ? 1 : 0;
}

// canonicalize pos and emb to fp32 scratch (exact conversion either way)
__global__ __launch_bounds__(256) void prep_kernel(
    const void* __restrict__ pos, const void* __restrict__ emb,
    const int* __restrict__ flags, float* __restrict__ posf, float* __restrict__ embf)
{
    const bool pb = flags[1] != 0, eb = flags[3] != 0;
    for (int i = threadIdx.x; i < Bsz * Ssz * 2; i += 256)
        posf[i] = pb ? loadf<true>(pos, i) : loadf<false>(pos, i);
    for (int i = threadIdx.x; i < NUMEMB * DKsz; i += 256)
        embf[i] = eb ? loadf<true>(emb, i) : loadf<false>(emb, i);
}

// ---------------- Projection GEMM: Y = X @ W^T + b -------------------------
// 128x128 block tile, BK=32, LDS-staged with fp32->bf16 convert on the staging
// write. 4 waves in 2x2; each wave computes 64x64 via 16 MFMAs/K-step.
template<bool XB, bool WB>
__device__ __forceinline__ void proj_body(
    const void* X, const void* W, const void* bias, void* Y, bool ybf,
    int bx, int by, short* As, short* Bs)
{
    const int tid  = threadIdx.x;
    const int wave = tid >> 6;
    const int lane = tid & 63;
    const int l15  = lane & 15;
    const int quad = lane >> 4;
    const int wm = wave & 1;
    const int wn = wave >> 1;
    const int m0 = bx * BM;
    const int n0 = by * BN;

    f32x4 acc[4][4];
#pragma unroll
    for (int i = 0; i < 4; i++)
#pragma unroll
        for (int j = 0; j < 4; j++) acc[i][j] = (f32x4)0.0f;

    const int r0 = tid >> 2;     // staging row 0..63 (and +64)
    const int cc = tid & 3;      // staging col-chunk (8 elems each)

    for (int kk = 0; kk < Dsz; kk += BK) {
        // global loads first: overlap with previous iteration's MFMA tail
        short8 va0 = load8bf<XB>(X, (size_t)(m0 + r0)      * Dsz + kk + cc * 8);
        short8 va1 = load8bf<XB>(X, (size_t)(m0 + 64 + r0) * Dsz + kk + cc * 8);
        short8 vb0 = load8bf<WB>(W, (size_t)(n0 + r0)      * Dsz + kk + cc * 8);
        short8 vb1 = load8bf<WB>(W, (size_t)(n0 + 64 + r0) * Dsz + kk + cc * 8);
        __syncthreads();   // previous iter's frag reads done before overwrite
        *(short8*)&As[(r0)      * LPAD + cc * 8] = va0;
        *(short8*)&As[(64 + r0) * LPAD + cc * 8] = va1;
        *(short8*)&Bs[(r0)      * LPAD + cc * 8] = vb0;
        *(short8*)&Bs[(64 + r0) * LPAD + cc * 8] = vb1;
        __syncthreads();

        short8 af[4], bf[4];
#pragma unroll
        for (int i = 0; i < 4; i++)
            af[i] = *(const short8*)&As[(wm * 64 + i * 16 + l15) * LPAD + quad * 8];
#pragma unroll
        for (int j = 0; j < 4; j++)
            bf[j] = *(const short8*)&Bs[(wn * 64 + j * 16 + l15) * LPAD + quad * 8];
#pragma unroll
        for (int i = 0; i < 4; i++)
#pragma unroll
            for (int j = 0; j < 4; j++)
                acc[i][j] = __builtin_amdgcn_mfma_f32_16x16x32_bf16(af[i], bf[j], acc[i][j], 0, 0, 0);
    }

#pragma unroll
    for (int j = 0; j < 4; j++) {
        const int n = n0 + wn * 64 + j * 16 + l15;
        const float bv_ = loadf<WB>(bias, n);   // biases are zeros; dtype-proof anyway
#pragma unroll
        for (int i = 0; i < 4; i++) {
#pragma unroll
            for (int r = 0; r < 4; r++) {
                const int m = m0 + wm * 64 + i * 16 + quad * 4 + r;
                const float val = acc[i][j][r] + bv_;
                if (ybf) ((__hip_bfloat16*)Y)[(size_t)m * Dsz + n] = __float2bfloat16(val);
                else     ((float*)Y)[(size_t)m * Dsz + n] = val;
            }
        }
    }
}

__global__ __launch_bounds__(256) void proj_kernel(
    const void* X0, const void* X1, const void* X2,
    const void* Wq, const void* bq, const void* Wk, const void* bk,
    const void* Wv, const void* bv,
    void* Qw, void* Kw, void* Vw, const int* __restrict__ flags)
{
    __shared__ __align__(16) short As[BM * LPAD];
    __shared__ __align__(16) short Bs[BN * LPAD];
    const int z = blockIdx.z;
    const void* X = (z == 0) ? X0 : ((z == 1) ? X1 : X2);
    const void* W = (z == 0) ? Wq : ((z == 1) ? Wk : Wv);
    const void* B = (z == 0) ? bq : ((z == 1) ? bk : bv);
    void* Y = (z == 0) ? Qw : ((z == 1) ? Kw : Vw);
    const bool xb = flags[0] != 0, wb = flags[2] != 0;
    // K/V always stored bf16 in ws; Q stored in the input (=output) dtype.
    const bool ybf = xb || (z != 0);
    if (xb) { if (wb) proj_body<true , true >(X, W, B, Y, ybf, blockIdx.x, blockIdx.y, As, Bs);
              else    proj_body<true , false>(X, W, B, Y, ybf, blockIdx.x, blockIdx.y, As, Bs); }
    else    { if (wb) proj_body<false, true >(X, W, B, Y, ybf, blockIdx.x, blockIdx.y, As, Bs);
              else    proj_body<false, false>(X, W, B, Y, ybf, blockIdx.x, blockIdx.y, As, Bs); }
}

// ---------------- Flash attention with distance-aware key bias --------------
template<bool QB>
__device__ __forceinline__ void attn_body(
    const void* Qw, const short* __restrict__ Ks, const short* __restrict__ Vs,
    const float* __restrict__ posf, const float* __restrict__ embf, void* out,
    unsigned short* Klds, unsigned short* Vtlds, unsigned short* Plds,
    float* qe, float* qpos, float* kpos)
{
    const int qt = blockIdx.x, h = blockIdx.y, b = blockIdx.z;
    const int tid  = threadIdx.x;
    const int wave = tid >> 6;
    const int lane = tid & 63;
    const int l15  = lane & 15;
    const int quad = lane >> 4;

    // stage q positions (fp32 canonical, exact)
    if (tid < 128) {
        const int row = tid >> 1, c = tid & 1;
        qpos[tid] = posf[((size_t)b * Ssz + qt * 64 + row) * 2 + c];
    }
    // qe[row][e] = sum_d Q[b, qrow, h*64+d] * emb[e][d]
    for (int p = tid; p < 64 * NUMEMB; p += 256) {
        const int row = p / NUMEMB, e = p - row * NUMEMB;
        const size_t qoff = ((size_t)b * Ssz + qt * 64 + row) * Dsz + h * DKsz;
        float s = 0.f;
#pragma unroll
        for (int c = 0; c < 8; c++) {
            short8 qv = load8bf<QB>(Qw, qoff + c * 8);
            const float* er = embf + e * DKsz + c * 8;
#pragma unroll
            for (int i = 0; i < 8; i++) s += bfbits2f(qv[i]) * er[i];
        }
        qe[p] = s;
    }

    // Q fragments (A-layout): row = l15, k = quad*8 + j
    short8 qfrag[2];
    {
        const size_t qbase = ((size_t)b * Ssz + qt * 64 + wave * 16 + l15) * Dsz + h * DKsz;
        qfrag[0] = load8bf<QB>(Qw, qbase + quad * 8);
        qfrag[1] = load8bf<QB>(Qw, qbase + 32 + quad * 8);
    }

    float m_run[4], l_run[4];
    f32x4 oacc[4];
#pragma unroll
    for (int r = 0; r < 4; r++) { m_run[r] = -1e30f; l_run[r] = 0.f; }
#pragma unroll
    for (int j = 0; j < 4; j++) oacc[j] = (f32x4)0.0f;

    const float MAXD = 141421.35623730951f;  // fp32(100000*sqrt(2))
    const float NINE = 9.0f;

    for (int it = 0; it < 16; it++) {
        __syncthreads();  // LDS reuse + first-iter qe/qpos visibility
        {
            int t = tid;
#pragma unroll
            for (int rep = 0; rep < 2; rep++, t += 256) {
                const int row = t >> 3, chunk = t & 7;
                short8 v = *(const short8*)(Ks + ((size_t)b * Ssz + it * 64 + row) * Dsz + h * DKsz + chunk * 8);
                *(short8*)&Klds[row * 72 + chunk * 8] = v;
            }
        }
        {
            int t = tid;
#pragma unroll
            for (int rep = 0; rep < 2; rep++, t += 256) {
                const int s = t >> 3, chunk = t & 7;
                short8 v = *(const short8*)(Vs + ((size_t)b * Ssz + it * 64 + s) * Dsz + h * DKsz + chunk * 8);
#pragma unroll
                for (int i = 0; i < 8; i++)
                    Vtlds[(chunk * 8 + i) * 72 + s] = (unsigned short)v[i];
            }
        }
        if (tid < 128) {
            const int row = tid >> 1, c = tid & 1;
            kpos[tid] = posf[((size_t)b * Ssz + it * 64 + row) * 2 + c];
        }
        __syncthreads();

        // S = Q K^T via MFMA
        f32x4 sf[4];
#pragma unroll
        for (int j = 0; j < 4; j++) sf[j] = (f32x4)0.0f;
#pragma unroll
        for (int st = 0; st < 2; st++) {
#pragma unroll
            for (int j = 0; j < 4; j++) {
                short8 kb = *(const short8*)&Klds[(j * 16 + l15) * 72 + st * 32 + quad * 8];
                sf[j] = __builtin_amdgcn_mfma_f32_16x16x32_bf16(qfrag[st], kb, sf[j], 0, 0, 0);
            }
        }

        // bias + scale. idx math matches np fp32 sequence exactly: no FMA.
        float sv[4][4];
#pragma unroll
        for (int r = 0; r < 4; r++) {
            const int m = wave * 16 + quad * 4 + r;
            const float qx = qpos[m * 2], qy = qpos[m * 2 + 1];
#pragma unroll
            for (int j = 0; j < 4; j++) {
                const int n = j * 16 + l15;
                const float dx = __fsub_rn(qx, kpos[n * 2]);
                const float dy = __fsub_rn(qy, kpos[n * 2 + 1]);
                const float ss = __fadd_rn(__fmul_rn(dx, dx), __fmul_rn(dy, dy));
                const float dist = __fdiv_rn(sqrtf(ss), MAXD);
                const float d9 = __fmul_rn(dist, NINE);
                int idx = (int)rintf(d9);
                idx = idx < 0 ? 0 : (idx > NUMEMB - 1 ? NUMEMB - 1 : idx);
                sv[r][j] = (sf[j][r] + qe[m * NUMEMB + idx]) * 0.125f;
            }
        }

        // online softmax per row (rows replicated across 16 lanes of a quad)
        float alpha[4];
#pragma unroll
        for (int r = 0; r < 4; r++) {
            float vmax = sv[r][0];
#pragma unroll
            for (int j = 1; j < 4; j++) vmax = fmaxf(vmax, sv[r][j]);
#pragma unroll
            for (int off = 1; off < 16; off <<= 1) vmax = fmaxf(vmax, __shfl_xor(vmax, off, 16));
            const float mnew = fmaxf(m_run[r], vmax);
            alpha[r] = __expf(m_run[r] - mnew);
            m_run[r] = mnew;
            float psum = 0.f;
#pragma unroll
            for (int j = 0; j < 4; j++) {
                const float p = __expf(sv[r][j] - mnew);
                sv[r][j] = p;
                psum += p;
            }
#pragma unroll
            for (int off = 1; off < 16; off <<= 1) psum += __shfl_xor(psum, off, 16);
            l_run[r] = l_run[r] * alpha[r] + psum;
        }
#pragma unroll
        for (int j = 0; j < 4; j++) {
            f32x4 o = oacc[j];
#pragma unroll
            for (int r = 0; r < 4; r++) o[r] *= alpha[r];
            oacc[j] = o;
        }

        // P (bf16) -> LDS; wave-private rows
#pragma unroll
        for (int r = 0; r < 4; r++) {
            const int m = wave * 16 + quad * 4 + r;
#pragma unroll
            for (int j = 0; j < 4; j++) {
                Plds[m * 72 + j * 16 + l15] = f2bf_bits(sv[r][j]);
            }
        }
        __syncthreads();

        // O += P @ V via MFMA
#pragma unroll
        for (int st = 0; st < 2; st++) {
            short8 pf = *(const short8*)&Plds[(wave * 16 + l15) * 72 + st * 32 + quad * 8];
#pragma unroll
            for (int j = 0; j < 4; j++) {
                short8 vb = *(const short8*)&Vtlds[(j * 16 + l15) * 72 + st * 32 + quad * 8];
                oacc[j] = __builtin_amdgcn_mfma_f32_16x16x32_bf16(pf, vb, oacc[j], 0, 0, 0);
            }
        }
    }

    __syncthreads();  // all Q reads of this block's region done before overwrite

#pragma unroll
    for (int r = 0; r < 4; r++) {
        const float inv = 1.0f / l_run[r];
        const int m = qt * 64 + wave * 16 + quad * 4 + r;
#pragma unroll
        for (int j = 0; j < 4; j++) {
            const int n = h * DKsz + j * 16 + l15;
            const float val = oacc[j][r] * inv;
            const size_t oidx = ((size_t)b * Ssz + m) * Dsz + n;
            if constexpr (QB) ((__hip_bfloat16*)out)[oidx] = __float2bfloat16(val);
            else              ((float*)out)[oidx] = val;
        }
    }
}

__global__ __launch_bounds__(256) void attn_kernel(
    const void* Qw, const short* __restrict__ Ks, const short* __restrict__ Vs,
    const float* __restrict__ posf, const float* __restrict__ embf, void* out,
    const int* __restrict__ flags)
{
    __shared__ __align__(16) unsigned short Klds[64 * 72];
    __shared__ __align__(16) unsigned short Vtlds[64 * 72];
    __shared__ __align__(16) unsigned short Plds[64 * 72];
    __shared__ __align__(16) float qe[64 * NUMEMB];
    __shared__ __align__(16) float qpos[64 * 2];
    __shared__ __align__(16) float kpos[64 * 2];

    if (flags[0] != 0)
        attn_body<true >(Qw, Ks, Vs, posf, embf, out, Klds, Vtlds, Plds, qe, qpos, kpos);
    else
        attn_body<false>(Qw, Ks, Vs, posf, embf, out, Klds, Vtlds, Plds, qe, qpos, kpos);
}

extern "C" void kernel_launch(void* const* d_in, const int* in_sizes, int n_in,
                              void* d_out, int out_size, void* d_ws, size_t ws_size,
                              hipStream_t stream) {
    const void* query = d_in[0];
    const void* key   = d_in[1];
    const void* value = d_in[2];
    const void* tpos  = d_in[3];
    const void* Wq    = d_in[4];
    const void* bq    = d_in[5];
    const void* Wk    = d_in[6];
    const void* bk    = d_in[7];
    const void* Wv    = d_in[8];
    const void* bv    = d_in[9];
    const void* emb   = d_in[10];

    int*   flags = (int*)d_ws;
    float* posf  = (float*)((char*)d_ws + POSF_OFF);
    float* embf  = (float*)((char*)d_ws + EMBF_OFF);
    void*  Kw    = (char*)d_ws + K_OFF;
    void*  Vw    = (char*)d_ws + V_OFF;
    void*  Qw    = d_out;   // Q staged in d_out (each attn block reads then
                            // overwrites only its own (b,row-tile,head) region)

    detect_kernel<<<4, 64, 0, stream>>>(
        (const unsigned int*)query, (const unsigned int*)tpos,
        (const unsigned int*)Wq, (const unsigned int*)emb, flags);

    prep_kernel<<<1, 256, 0, stream>>>(tpos, emb, flags, posf, embf);

    // projections: grid (M/128, N/128, 3)
    proj_kernel<<<dim3(32, 6, 3), 256, 0, stream>>>(
        query, key, value, Wq, bq, Wk, bk, Wv, bv, Qw, Kw, Vw, flags);

    // attention: grid (S/64 q-tiles, H, B)
    attn_kernel<<<dim3(16, Hn, Bsz), 256, 0, stream>>>(
        Qw, (const short*)Kw, (const short*)Vw, posf, embf, d_out, flags);
}

// Round 5
// 262.011 us; speedup vs baseline: 1.7643x; 1.1040x over previous
//
#include <hip/hip_runtime.h>
#include <hip/hip_bf16.h>

#define Bsz 4
#define Ssz 1024
#define Dsz 768
#define Hn 12
#define DKsz 64
#define NUMEMB 10

// d_ws layout (bytes)
#define POSF_OFF 64
#define EMBF_OFF 32832          // 64 + 8192*4
#define IDX_OFF  35392          // EMBF_OFF + 640*4
#define K_OFF    4229696        // IDX_OFF + 4*1024*1024
#define V_OFF    10521152       // K_OFF + 4*1024*768*2

// proj GEMM tile config
#define BM 128
#define BN 128
#define BK 32
#define LPAD 40                 // LDS row stride (elems): 32 + 8 pad

#define IPAD 80                 // idx tile row stride (bytes), 16B-aligned

typedef __attribute__((ext_vector_type(8))) short short8;
typedef __attribute__((ext_vector_type(8))) float float8;
typedef __attribute__((ext_vector_type(4))) float f32x4;
typedef __attribute__((ext_vector_type(4))) unsigned int u32x4;

__device__ __forceinline__ float bfbits2f(short u) {
    union { unsigned int i; float f; } v;
    v.i = ((unsigned int)(unsigned short)u) << 16;
    return v.f;
}
__device__ __forceinline__ unsigned short f2bf_bits(float f) {
    __hip_bfloat16 h = __float2bfloat16(f);
    return *reinterpret_cast<unsigned short*>(&h);
}

// dtype-dispatched loads: idx is an ELEMENT index (same for both dtypes)
template<bool BF16>
__device__ __forceinline__ float loadf(const void* base, size_t idx) {
    if constexpr (BF16) return __bfloat162float(((const __hip_bfloat16*)base)[idx]);
    else return ((const float*)base)[idx];
}
template<bool BF16>
__device__ __forceinline__ short8 load8bf(const void* base, size_t idx) {
    if constexpr (BF16) {
        return *(const short8*)((const short*)base + idx);
    } else {
        float8 f = *(const float8*)((const float*)base + idx);
        short8 r;
#pragma unroll
        for (int i = 0; i < 8; i++) r[i] = (short)f2bf_bits(f[i]);
        return r;
    }
}

// ---------------- dtype detector ------------------------------------------
__global__ __launch_bounds__(64) void detect_kernel(
    const unsigned int* __restrict__ q, const unsigned int* __restrict__ p,
    const unsigned int* __restrict__ w, const unsigned int* __restrict__ e,
    int* __restrict__ flags)
{
    const int which = blockIdx.x;
    const unsigned int* ptr = (which == 0) ? q : ((which == 1) ? p : ((which == 2) ? w : e));
    const int n = (which == 3) ? 320 : ((which == 1) ? 4096 : 1024);
    int cnt = 0;
    for (int i = threadIdx.x; i < n; i += 64) {
        const unsigned int ex = (ptr[i] >> 7) & 0xFF;
        cnt += (ex >= 110 && ex <= 145) ? 1 : 0;
    }
#pragma unroll
    for (int off = 1; off < 64; off <<= 1) cnt += __shfl_xor(cnt, off, 64);
    if (threadIdx.x == 0) flags[which] = (2 * cnt > n) ? 1 : 0;
}

// canonicalize pos and emb to fp32 scratch (exact conversion either way)
__global__ __launch_bounds__(256) void prep_kernel(
    const void* __restrict__ pos, const void* __restrict__ emb,
    const int* __restrict__ flags, float* __restrict__ posf, float* __restrict__ embf)
{
    const bool pb = flags[1] != 0, eb = flags[3] != 0;
    const int t0 = blockIdx.x * 256 + threadIdx.x;
    for (int i = t0; i < Bsz * Ssz * 2; i += 1024)
        posf[i] = pb ? loadf<true>(pos, i) : loadf<false>(pos, i);
    for (int i = t0; i < NUMEMB * DKsz; i += 1024)
        embf[i] = eb ? loadf<true>(emb, i) : loadf<false>(emb, i);
}

// ---------------- idx precompute: idx[b][q][k], uint8 ----------------------
// Exact fp32 op chain matching numpy (no FMA contraction). Head-independent,
// computed ONCE here instead of 12x inside attention.
__global__ __launch_bounds__(256) void idx_kernel(
    const float* __restrict__ posf, unsigned char* __restrict__ idxb)
{
    const int kt = blockIdx.x, qt = blockIdx.y, b = blockIdx.z;
    const int t = threadIdx.x;
    const int r = t >> 2, cc = t & 3;
    const int q = qt * 64 + r;
    const float qx = posf[((size_t)b * Ssz + q) * 2];
    const float qy = posf[((size_t)b * Ssz + q) * 2 + 1];
    const float MAXD = 141421.35623730951f;  // fp32(100000*sqrt(2))
    const int k0 = kt * 64 + cc * 16;
    unsigned int w[4];
#pragma unroll
    for (int g = 0; g < 4; g++) {
        unsigned int acc = 0;
#pragma unroll
        for (int u = 0; u < 4; u++) {
            const int k = k0 + g * 4 + u;
            const float kx = posf[((size_t)b * Ssz + k) * 2];
            const float ky = posf[((size_t)b * Ssz + k) * 2 + 1];
            const float dx = __fsub_rn(qx, kx);
            const float dy = __fsub_rn(qy, ky);
            const float ss = __fadd_rn(__fmul_rn(dx, dx), __fmul_rn(dy, dy));
            const float dist = __fdiv_rn(sqrtf(ss), MAXD);
            const float d9 = __fmul_rn(dist, 9.0f);
            int idx = (int)rintf(d9);
            idx = idx < 0 ? 0 : (idx > NUMEMB - 1 ? NUMEMB - 1 : idx);
            acc |= ((unsigned int)idx) << (8 * u);
        }
        w[g] = acc;
    }
    u32x4 v; v[0] = w[0]; v[1] = w[1]; v[2] = w[2]; v[3] = w[3];
    *(u32x4*)(idxb + ((size_t)(b * Ssz + q)) * Ssz + k0) = v;
}

// ---------------- Projection GEMM: Y = X @ W^T + b -------------------------
template<bool XB, bool WB>
__device__ __forceinline__ void proj_body(
    const void* X, const void* W, const void* bias, void* Y, bool ybf,
    int bx, int by, short* As, short* Bs)
{
    const int tid  = threadIdx.x;
    const int wave = tid >> 6;
    const int lane = tid & 63;
    const int l15  = lane & 15;
    const int quad = lane >> 4;
    const int wm = wave & 1;
    const int wn = wave >> 1;
    const int m0 = bx * BM;
    const int n0 = by * BN;

    f32x4 acc[4][4];
#pragma unroll
    for (int i = 0; i < 4; i++)
#pragma unroll
        for (int j = 0; j < 4; j++) acc[i][j] = (f32x4)0.0f;

    const int r0 = tid >> 2;     // staging row 0..63 (and +64)
    const int cc = tid & 3;      // staging col-chunk (8 elems each)

    for (int kk = 0; kk < Dsz; kk += BK) {
        short8 va0 = load8bf<XB>(X, (size_t)(m0 + r0)      * Dsz + kk + cc * 8);
        short8 va1 = load8bf<XB>(X, (size_t)(m0 + 64 + r0) * Dsz + kk + cc * 8);
        short8 vb0 = load8bf<WB>(W, (size_t)(n0 + r0)      * Dsz + kk + cc * 8);
        short8 vb1 = load8bf<WB>(W, (size_t)(n0 + 64 + r0) * Dsz + kk + cc * 8);
        __syncthreads();
        *(short8*)&As[(r0)      * LPAD + cc * 8] = va0;
        *(short8*)&As[(64 + r0) * LPAD + cc * 8] = va1;
        *(short8*)&Bs[(r0)      * LPAD + cc * 8] = vb0;
        *(short8*)&Bs[(64 + r0) * LPAD + cc * 8] = vb1;
        __syncthreads();

        short8 af[4], bf[4];
#pragma unroll
        for (int i = 0; i < 4; i++)
            af[i] = *(const short8*)&As[(wm * 64 + i * 16 + l15) * LPAD + quad * 8];
#pragma unroll
        for (int j = 0; j < 4; j++)
            bf[j] = *(const short8*)&Bs[(wn * 64 + j * 16 + l15) * LPAD + quad * 8];
#pragma unroll
        for (int i = 0; i < 4; i++)
#pragma unroll
            for (int j = 0; j < 4; j++)
                acc[i][j] = __builtin_amdgcn_mfma_f32_16x16x32_bf16(af[i], bf[j], acc[i][j], 0, 0, 0);
    }

#pragma unroll
    for (int j = 0; j < 4; j++) {
        const int n = n0 + wn * 64 + j * 16 + l15;
        const float bv_ = loadf<WB>(bias, n);
#pragma unroll
        for (int i = 0; i < 4; i++) {
#pragma unroll
            for (int r = 0; r < 4; r++) {
                const int m = m0 + wm * 64 + i * 16 + quad * 4 + r;
                const float val = acc[i][j][r] + bv_;
                if (ybf) ((__hip_bfloat16*)Y)[(size_t)m * Dsz + n] = __float2bfloat16(val);
                else     ((float*)Y)[(size_t)m * Dsz + n] = val;
            }
        }
    }
}

__global__ __launch_bounds__(256) void proj_kernel(
    const void* X0, const void* X1, const void* X2,
    const void* Wq, const void* bq, const void* Wk, const void* bk,
    const void* Wv, const void* bv,
    void* Qw, void* Kw, void* Vw, const int* __restrict__ flags)
{
    __shared__ __align__(16) short As[BM * LPAD];
    __shared__ __align__(16) short Bs[BN * LPAD];
    const int z = blockIdx.z;
    const void* X = (z == 0) ? X0 : ((z == 1) ? X1 : X2);
    const void* W = (z == 0) ? Wq : ((z == 1) ? Wk : Wv);
    const void* B = (z == 0) ? bq : ((z == 1) ? bk : bv);
    void* Y = (z == 0) ? Qw : ((z == 1) ? Kw : Vw);
    const bool xb = flags[0] != 0, wb = flags[2] != 0;
    const bool ybf = xb || (z != 0);
    if (xb) { if (wb) proj_body<true , true >(X, W, B, Y, ybf, blockIdx.x, blockIdx.y, As, Bs);
              else    proj_body<true , false>(X, W, B, Y, ybf, blockIdx.x, blockIdx.y, As, Bs); }
    else    { if (wb) proj_body<false, true >(X, W, B, Y, ybf, blockIdx.x, blockIdx.y, As, Bs);
              else    proj_body<false, false>(X, W, B, Y, ybf, blockIdx.x, blockIdx.y, As, Bs); }
}

// ---------------- Flash attention with distance-aware key bias --------------
template<bool QB>
__device__ __forceinline__ void attn_body(
    const void* Qw, const short* __restrict__ Ks, const short* __restrict__ Vs,
    const unsigned char* __restrict__ idxb, const float* __restrict__ embf, void* out,
    unsigned short* Klds, unsigned short* Vtlds, unsigned short* Plds,
    float* qe, unsigned char* Ilds)
{
    const int qt = blockIdx.x, h = blockIdx.y, b = blockIdx.z;
    const int tid  = threadIdx.x;
    const int wave = tid >> 6;
    const int lane = tid & 63;
    const int l15  = lane & 15;
    const int quad = lane >> 4;

    // qe[row][e] = sum_d Q[b, qrow, h*64+d] * emb[e][d]
    for (int p = tid; p < 64 * NUMEMB; p += 256) {
        const int row = p / NUMEMB, e = p - row * NUMEMB;
        const size_t qoff = ((size_t)b * Ssz + qt * 64 + row) * Dsz + h * DKsz;
        float s = 0.f;
#pragma unroll
        for (int c = 0; c < 8; c++) {
            short8 qv = load8bf<QB>(Qw, qoff + c * 8);
            const float* er = embf + e * DKsz + c * 8;
#pragma unroll
            for (int i = 0; i < 8; i++) s += bfbits2f(qv[i]) * er[i];
        }
        qe[p] = s;
    }

    // Q fragments (A-layout): row = l15, k = quad*8 + j
    short8 qfrag[2];
    {
        const size_t qbase = ((size_t)b * Ssz + qt * 64 + wave * 16 + l15) * Dsz + h * DKsz;
        qfrag[0] = load8bf<QB>(Qw, qbase + quad * 8);
        qfrag[1] = load8bf<QB>(Qw, qbase + 32 + quad * 8);
    }

    float m_run[4], l_run[4];
    f32x4 oacc[4];
#pragma unroll
    for (int r = 0; r < 4; r++) { m_run[r] = -1e30f; l_run[r] = 0.f; }
#pragma unroll
    for (int j = 0; j < 4; j++) oacc[j] = (f32x4)0.0f;

    for (int it = 0; it < 16; it++) {
        __syncthreads();  // prior-iter LDS reads done + first-iter qe visibility
        // K tile [64 keys][64 dk], stride 72, vector writes
        {
            int t = tid;
#pragma unroll
            for (int rep = 0; rep < 2; rep++, t += 256) {
                const int row = t >> 3, chunk = t & 7;
                short8 v = *(const short8*)(Ks + ((size_t)b * Ssz + it * 64 + row) * Dsz + h * DKsz + chunk * 8);
                *(short8*)&Klds[row * 72 + chunk * 8] = v;
            }
        }
        // V transposed, XOR-swizzled: element (d, s) at [d*72 + (s ^ ((d>>3)<<3))]
        {
            int t = tid;
#pragma unroll
            for (int rep = 0; rep < 2; rep++, t += 256) {
                const int s = t >> 3, chunk = t & 7;
                short8 v = *(const short8*)(Vs + ((size_t)b * Ssz + it * 64 + s) * Dsz + h * DKsz + chunk * 8);
                const int ssw = s ^ (chunk << 3);
#pragma unroll
                for (int i = 0; i < 8; i++)
                    Vtlds[(chunk * 8 + i) * 72 + ssw] = (unsigned short)v[i];
            }
        }
        // idx tile [64 q][64 k], row stride IPAD
        {
            const int row = tid >> 2, chunk = tid & 3;
            const u32x4 v = *(const u32x4*)(idxb + ((size_t)(b * Ssz + qt * 64 + row)) * Ssz + it * 64 + chunk * 16);
            *(u32x4*)&Ilds[row * IPAD + chunk * 16] = v;
        }
        __syncthreads();

        // S = Q K^T via MFMA
        f32x4 sf[4];
#pragma unroll
        for (int j = 0; j < 4; j++) sf[j] = (f32x4)0.0f;
#pragma unroll
        for (int st = 0; st < 2; st++) {
#pragma unroll
            for (int j = 0; j < 4; j++) {
                short8 kb = *(const short8*)&Klds[(j * 16 + l15) * 72 + st * 32 + quad * 8];
                sf[j] = __builtin_amdgcn_mfma_f32_16x16x32_bf16(qfrag[st], kb, sf[j], 0, 0, 0);
            }
        }

        // bias via precomputed idx (1 byte load replaces the distance chain)
        float sv[4][4];
#pragma unroll
        for (int r = 0; r < 4; r++) {
            const int m = wave * 16 + quad * 4 + r;
#pragma unroll
            for (int j = 0; j < 4; j++) {
                const int n = j * 16 + l15;
                const int idx = Ilds[m * IPAD + n];
                sv[r][j] = (sf[j][r] + qe[m * NUMEMB + idx]) * 0.125f;
            }
        }

        // online softmax per row (rows replicated across 16 lanes of a quad)
        float alpha[4];
#pragma unroll
        for (int r = 0; r < 4; r++) {
            float vmax = sv[r][0];
#pragma unroll
            for (int j = 1; j < 4; j++) vmax = fmaxf(vmax, sv[r][j]);
#pragma unroll
            for (int off = 1; off < 16; off <<= 1) vmax = fmaxf(vmax, __shfl_xor(vmax, off, 16));
            const float mnew = fmaxf(m_run[r], vmax);
            alpha[r] = __expf(m_run[r] - mnew);
            m_run[r] = mnew;
            float psum = 0.f;
#pragma unroll
            for (int j = 0; j < 4; j++) {
                const float p = __expf(sv[r][j] - mnew);
                sv[r][j] = p;
                psum += p;
            }
#pragma unroll
            for (int off = 1; off < 16; off <<= 1) psum += __shfl_xor(psum, off, 16);
            l_run[r] = l_run[r] * alpha[r] + psum;
        }
#pragma unroll
        for (int j = 0; j < 4; j++) {
            f32x4 o = oacc[j];
#pragma unroll
            for (int r = 0; r < 4; r++) o[r] *= alpha[r];
            oacc[j] = o;
        }

        // P (bf16) -> LDS, XOR-swizzled: element (m, c) at [m*72 + (c ^ (((m>>2)&3)<<4))]
        // wave-private rows -> no barrier needed before PV reads
#pragma unroll
        for (int r = 0; r < 4; r++) {
            const int m = wave * 16 + quad * 4 + r;
#pragma unroll
            for (int j = 0; j < 4; j++) {
                const int csw = (j * 16 + l15) ^ (quad << 4);
                Plds[m * 72 + csw] = f2bf_bits(sv[r][j]);
            }
        }

        // O += P @ V via MFMA
#pragma unroll
        for (int st = 0; st < 2; st++) {
            const int prow = wave * 16 + l15;
            const int pcsw = (st * 32 + quad * 8) ^ ((l15 >> 2) << 4);
            short8 pf = *(const short8*)&Plds[prow * 72 + pcsw];
#pragma unroll
            for (int j = 0; j < 4; j++) {
                const int d = j * 16 + l15;
                const int vsw = (st * 32 + quad * 8) ^ (((d >> 3) & 7) << 3);
                short8 vb = *(const short8*)&Vtlds[d * 72 + vsw];
                oacc[j] = __builtin_amdgcn_mfma_f32_16x16x32_bf16(pf, vb, oacc[j], 0, 0, 0);
            }
        }
    }

    __syncthreads();  // all Q reads of this block's region done before overwrite

#pragma unroll
    for (int r = 0; r < 4; r++) {
        const float inv = 1.0f / l_run[r];
        const int m = qt * 64 + wave * 16 + quad * 4 + r;
#pragma unroll
        for (int j = 0; j < 4; j++) {
            const int n = h * DKsz + j * 16 + l15;
            const float val = oacc[j][r] * inv;
            const size_t oidx = ((size_t)b * Ssz + m) * Dsz + n;
            if constexpr (QB) ((__hip_bfloat16*)out)[oidx] = __float2bfloat16(val);
            else              ((float*)out)[oidx] = val;
        }
    }
}

__global__ __launch_bounds__(256) void attn_kernel(
    const void* Qw, const short* __restrict__ Ks, const short* __restrict__ Vs,
    const unsigned char* __restrict__ idxb, const float* __restrict__ embf, void* out,
    const int* __restrict__ flags)
{
    __shared__ __align__(16) unsigned short Klds[64 * 72];
    __shared__ __align__(16) unsigned short Vtlds[64 * 72];
    __shared__ __align__(16) unsigned short Plds[64 * 72];
    __shared__ __align__(16) float qe[64 * NUMEMB];
    __shared__ __align__(16) unsigned char Ilds[64 * IPAD];

    if (flags[0] != 0)
        attn_body<true >(Qw, Ks, Vs, idxb, embf, out, Klds, Vtlds, Plds, qe, Ilds);
    else
        attn_body<false>(Qw, Ks, Vs, idxb, embf, out, Klds, Vtlds, Plds, qe, Ilds);
}

extern "C" void kernel_launch(void* const* d_in, const int* in_sizes, int n_in,
                              void* d_out, int out_size, void* d_ws, size_t ws_size,
                              hipStream_t stream) {
    const void* query = d_in[0];
    const void* key   = d_in[1];
    const void* value = d_in[2];
    const void* tpos  = d_in[3];
    const void* Wq    = d_in[4];
    const void* bq    = d_in[5];
    const void* Wk    = d_in[6];
    const void* bk    = d_in[7];
    const void* Wv    = d_in[8];
    const void* bv    = d_in[9];
    const void* emb   = d_in[10];

    int*           flags = (int*)d_ws;
    float*         posf  = (float*)((char*)d_ws + POSF_OFF);
    float*         embf  = (float*)((char*)d_ws + EMBF_OFF);
    unsigned char* idxb  = (unsigned char*)d_ws + IDX_OFF;
    void*          Kw    = (char*)d_ws + K_OFF;
    void*          Vw    = (char*)d_ws + V_OFF;
    void*          Qw    = d_out;   // Q staged in d_out

    detect_kernel<<<4, 64, 0, stream>>>(
        (const unsigned int*)query, (const unsigned int*)tpos,
        (const unsigned int*)Wq, (const unsigned int*)emb, flags);

    prep_kernel<<<4, 256, 0, stream>>>(tpos, emb, flags, posf, embf);

    idx_kernel<<<dim3(16, 16, Bsz), 256, 0, stream>>>(posf, idxb);

    proj_kernel<<<dim3(32, 6, 3), 256, 0, stream>>>(
        query, key, value, Wq, bq, Wk, bk, Wv, bv, Qw, Kw, Vw, flags);

    attn_kernel<<<dim3(16, Hn, Bsz), 256, 0, stream>>>(
        Qw, (const short*)Kw, (const short*)Vw, idxb, embf, d_out, flags);
}

// Round 6
// 241.334 us; speedup vs baseline: 1.9155x; 1.0857x over previous
//
#include <hip/hip_runtime.h>
#include <hip/hip_bf16.h>

#define Bsz 4
#define Ssz 1024
#define Dsz 768
#define Hn 12
#define DKsz 64
#define NUMEMB 10

// d_ws layout (bytes)
#define POSF_OFF 64
#define EMBF_OFF 32832          // 64 + 8192*4
#define IDX_OFF  35392          // EMBF_OFF + 640*4
#define K_OFF    4229696        // IDX_OFF + 4*1024*1024
#define V_OFF    10521152       // K_OFF + 4*1024*768*2

// proj GEMM tile config: 64(M) x 128(N), grid (64,6,3) = 1152 blocks
#define BM 64
#define BN 128
#define BK 32
#define LPAD 40                 // LDS row stride (elems): 32 + 8 pad

#define IPAD 80                 // idx tile row stride (bytes), 16B-aligned

typedef __attribute__((ext_vector_type(8))) short short8;
typedef __attribute__((ext_vector_type(8))) float float8;
typedef __attribute__((ext_vector_type(4))) float f32x4;
typedef __attribute__((ext_vector_type(4))) unsigned int u32x4;

__device__ __forceinline__ float bfbits2f(short u) {
    union { unsigned int i; float f; } v;
    v.i = ((unsigned int)(unsigned short)u) << 16;
    return v.f;
}
__device__ __forceinline__ unsigned short f2bf_bits(float f) {
    __hip_bfloat16 h = __float2bfloat16(f);
    return *reinterpret_cast<unsigned short*>(&h);
}

// dtype-dispatched loads: idx is an ELEMENT index (same for both dtypes)
template<bool BF16>
__device__ __forceinline__ float loadf(const void* base, size_t idx) {
    if constexpr (BF16) return __bfloat162float(((const __hip_bfloat16*)base)[idx]);
    else return ((const float*)base)[idx];
}
template<bool BF16>
__device__ __forceinline__ short8 load8bf(const void* base, size_t idx) {
    if constexpr (BF16) {
        return *(const short8*)((const short*)base + idx);
    } else {
        float8 f = *(const float8*)((const float*)base + idx);
        short8 r;
#pragma unroll
        for (int i = 0; i < 8; i++) r[i] = (short)f2bf_bits(f[i]);
        return r;
    }
}

// ---------------- dtype detector ------------------------------------------
__global__ __launch_bounds__(64) void detect_kernel(
    const unsigned int* __restrict__ q, const unsigned int* __restrict__ p,
    const unsigned int* __restrict__ w, const unsigned int* __restrict__ e,
    int* __restrict__ flags)
{
    const int which = blockIdx.x;
    const unsigned int* ptr = (which == 0) ? q : ((which == 1) ? p : ((which == 2) ? w : e));
    const int n = (which == 3) ? 320 : ((which == 1) ? 4096 : 1024);
    int cnt = 0;
    for (int i = threadIdx.x; i < n; i += 64) {
        const unsigned int ex = (ptr[i] >> 7) & 0xFF;
        cnt += (ex >= 110 && ex <= 145) ? 1 : 0;
    }
#pragma unroll
    for (int off = 1; off < 64; off <<= 1) cnt += __shfl_xor(cnt, off, 64);
    if (threadIdx.x == 0) flags[which] = (2 * cnt > n) ? 1 : 0;
}

// canonicalize pos and emb to fp32 scratch (exact conversion either way)
__global__ __launch_bounds__(256) void prep_kernel(
    const void* __restrict__ pos, const void* __restrict__ emb,
    const int* __restrict__ flags, float* __restrict__ posf, float* __restrict__ embf)
{
    const bool pb = flags[1] != 0, eb = flags[3] != 0;
    const int t0 = blockIdx.x * 256 + threadIdx.x;
    for (int i = t0; i < Bsz * Ssz * 2; i += 1024)
        posf[i] = pb ? loadf<true>(pos, i) : loadf<false>(pos, i);
    for (int i = t0; i < NUMEMB * DKsz; i += 1024)
        embf[i] = eb ? loadf<true>(emb, i) : loadf<false>(emb, i);
}

// ---------------- idx precompute: idx[b][q][k], uint8 ----------------------
__global__ __launch_bounds__(256) void idx_kernel(
    const float* __restrict__ posf, unsigned char* __restrict__ idxb)
{
    const int kt = blockIdx.x, qt = blockIdx.y, b = blockIdx.z;
    const int t = threadIdx.x;
    const int r = t >> 2, cc = t & 3;
    const int q = qt * 64 + r;
    const float qx = posf[((size_t)b * Ssz + q) * 2];
    const float qy = posf[((size_t)b * Ssz + q) * 2 + 1];
    const float MAXD = 141421.35623730951f;  // fp32(100000*sqrt(2))
    const int k0 = kt * 64 + cc * 16;
    unsigned int w[4];
#pragma unroll
    for (int g = 0; g < 4; g++) {
        unsigned int acc = 0;
#pragma unroll
        for (int u = 0; u < 4; u++) {
            const int k = k0 + g * 4 + u;
            const float kx = posf[((size_t)b * Ssz + k) * 2];
            const float ky = posf[((size_t)b * Ssz + k) * 2 + 1];
            const float dx = __fsub_rn(qx, kx);
            const float dy = __fsub_rn(qy, ky);
            const float ss = __fadd_rn(__fmul_rn(dx, dx), __fmul_rn(dy, dy));
            const float dist = __fdiv_rn(sqrtf(ss), MAXD);
            const float d9 = __fmul_rn(dist, 9.0f);
            int idx = (int)rintf(d9);
            idx = idx < 0 ? 0 : (idx > NUMEMB - 1 ? NUMEMB - 1 : idx);
            acc |= ((unsigned int)idx) << (8 * u);
        }
        w[g] = acc;
    }
    u32x4 v; v[0] = w[0]; v[1] = w[1]; v[2] = w[2]; v[3] = w[3];
    *(u32x4*)(idxb + ((size_t)(b * Ssz + q)) * Ssz + k0) = v;
}

// ---------------- Projection GEMM: Y = X @ W^T + b -------------------------
// 64x128 block tile, 4 waves 2x2 each 32x64. Register-prefetch pipelined.
template<bool XB, bool WB>
__device__ __forceinline__ void proj_body(
    const void* X, const void* W, const void* bias, void* Y, bool ybf,
    int bx, int by, short* As, short* Bs)
{
    const int tid  = threadIdx.x;
    const int wave = tid >> 6;
    const int lane = tid & 63;
    const int l15  = lane & 15;
    const int quad = lane >> 4;
    const int wm = wave & 1;
    const int wn = wave >> 1;
    const int m0 = bx * BM;
    const int n0 = by * BN;

    f32x4 acc[2][4];
#pragma unroll
    for (int i = 0; i < 2; i++)
#pragma unroll
        for (int j = 0; j < 4; j++) acc[i][j] = (f32x4)0.0f;

    const int r0 = tid >> 2;     // staging row 0..63
    const int cc = tid & 3;      // staging col-chunk (8 elems)

    // preload kk=0
    short8 pa  = load8bf<XB>(X, (size_t)(m0 + r0)      * Dsz + cc * 8);
    short8 pb0 = load8bf<WB>(W, (size_t)(n0 + r0)      * Dsz + cc * 8);
    short8 pb1 = load8bf<WB>(W, (size_t)(n0 + 64 + r0) * Dsz + cc * 8);

    for (int kk = 0; kk < Dsz; kk += BK) {
        __syncthreads();   // prior iter's frag reads done
        *(short8*)&As[(r0)      * LPAD + cc * 8] = pa;
        *(short8*)&Bs[(r0)      * LPAD + cc * 8] = pb0;
        *(short8*)&Bs[(64 + r0) * LPAD + cc * 8] = pb1;
        __syncthreads();

        if (kk + BK < Dsz) {   // prefetch next tile; flies during MFMA below
            pa  = load8bf<XB>(X, (size_t)(m0 + r0)      * Dsz + kk + BK + cc * 8);
            pb0 = load8bf<WB>(W, (size_t)(n0 + r0)      * Dsz + kk + BK + cc * 8);
            pb1 = load8bf<WB>(W, (size_t)(n0 + 64 + r0) * Dsz + kk + BK + cc * 8);
        }

        short8 af[2], bf[4];
#pragma unroll
        for (int i = 0; i < 2; i++)
            af[i] = *(const short8*)&As[(wm * 32 + i * 16 + l15) * LPAD + quad * 8];
#pragma unroll
        for (int j = 0; j < 4; j++)
            bf[j] = *(const short8*)&Bs[(wn * 64 + j * 16 + l15) * LPAD + quad * 8];
#pragma unroll
        for (int i = 0; i < 2; i++)
#pragma unroll
            for (int j = 0; j < 4; j++)
                acc[i][j] = __builtin_amdgcn_mfma_f32_16x16x32_bf16(af[i], bf[j], acc[i][j], 0, 0, 0);
    }

#pragma unroll
    for (int j = 0; j < 4; j++) {
        const int n = n0 + wn * 64 + j * 16 + l15;
        const float bv_ = loadf<WB>(bias, n);
#pragma unroll
        for (int i = 0; i < 2; i++) {
#pragma unroll
            for (int r = 0; r < 4; r++) {
                const int m = m0 + wm * 32 + i * 16 + quad * 4 + r;
                const float val = acc[i][j][r] + bv_;
                if (ybf) ((__hip_bfloat16*)Y)[(size_t)m * Dsz + n] = __float2bfloat16(val);
                else     ((float*)Y)[(size_t)m * Dsz + n] = val;
            }
        }
    }
}

__global__ __launch_bounds__(256) void proj_kernel(
    const void* X0, const void* X1, const void* X2,
    const void* Wq, const void* bq, const void* Wk, const void* bk,
    const void* Wv, const void* bv,
    void* Qw, void* Kw, void* Vw, const int* __restrict__ flags)
{
    __shared__ __align__(16) short As[BM * LPAD];
    __shared__ __align__(16) short Bs[BN * LPAD];
    const int z = blockIdx.z;
    const void* X = (z == 0) ? X0 : ((z == 1) ? X1 : X2);
    const void* W = (z == 0) ? Wq : ((z == 1) ? Wk : Wv);
    const void* B = (z == 0) ? bq : ((z == 1) ? bk : bv);
    void* Y = (z == 0) ? Qw : ((z == 1) ? Kw : Vw);
    const bool xb = flags[0] != 0, wb = flags[2] != 0;
    const bool ybf = xb || (z != 0);
    if (xb) { if (wb) proj_body<true , true >(X, W, B, Y, ybf, blockIdx.x, blockIdx.y, As, Bs);
              else    proj_body<true , false>(X, W, B, Y, ybf, blockIdx.x, blockIdx.y, As, Bs); }
    else    { if (wb) proj_body<false, true >(X, W, B, Y, ybf, blockIdx.x, blockIdx.y, As, Bs);
              else    proj_body<false, false>(X, W, B, Y, ybf, blockIdx.x, blockIdx.y, As, Bs); }
}

// ---------------- Flash attention with distance-aware key bias --------------
// Register-prefetch pipelined: iter it+1's K/V/idx global loads fly during
// iter it's compute.
template<bool QB>
__device__ __forceinline__ void attn_body(
    const void* Qw, const short* __restrict__ Ks, const short* __restrict__ Vs,
    const unsigned char* __restrict__ idxb, const float* __restrict__ embf, void* out,
    unsigned short* Klds, unsigned short* Vtlds, unsigned short* Plds,
    float* qe, unsigned char* Ilds)
{
    const int qt = blockIdx.x, h = blockIdx.y, b = blockIdx.z;
    const int tid  = threadIdx.x;
    const int wave = tid >> 6;
    const int lane = tid & 63;
    const int l15  = lane & 15;
    const int quad = lane >> 4;

    // qe[row][e] = sum_d Q[b, qrow, h*64+d] * emb[e][d]
    for (int p = tid; p < 64 * NUMEMB; p += 256) {
        const int row = p / NUMEMB, e = p - row * NUMEMB;
        const size_t qoff = ((size_t)b * Ssz + qt * 64 + row) * Dsz + h * DKsz;
        float s = 0.f;
#pragma unroll
        for (int c = 0; c < 8; c++) {
            short8 qv = load8bf<QB>(Qw, qoff + c * 8);
            const float* er = embf + e * DKsz + c * 8;
#pragma unroll
            for (int i = 0; i < 8; i++) s += bfbits2f(qv[i]) * er[i];
        }
        qe[p] = s;
    }

    // Q fragments (A-layout): row = l15, k = quad*8 + j
    short8 qfrag[2];
    {
        const size_t qbase = ((size_t)b * Ssz + qt * 64 + wave * 16 + l15) * Dsz + h * DKsz;
        qfrag[0] = load8bf<QB>(Qw, qbase + quad * 8);
        qfrag[1] = load8bf<QB>(Qw, qbase + 32 + quad * 8);
    }

    float m_run[4], l_run[4];
    f32x4 oacc[4];
#pragma unroll
    for (int r = 0; r < 4; r++) { m_run[r] = -1e30f; l_run[r] = 0.f; }
#pragma unroll
    for (int j = 0; j < 4; j++) oacc[j] = (f32x4)0.0f;

    // staging lane mapping
    const int srow = tid >> 3, schk = tid & 7;      // K/V: row 0..31(+32), chunk 0..7
    const int irow = tid >> 2, ichk = tid & 3;      // idx: row 0..63, chunk 0..3

    // preload it=0 into registers
    short8 pk0, pk1, pv0, pv1;
    u32x4 pidx;
    {
        pk0 = *(const short8*)(Ks + ((size_t)b * Ssz + srow)      * Dsz + h * DKsz + schk * 8);
        pk1 = *(const short8*)(Ks + ((size_t)b * Ssz + 32 + srow) * Dsz + h * DKsz + schk * 8);
        pv0 = *(const short8*)(Vs + ((size_t)b * Ssz + srow)      * Dsz + h * DKsz + schk * 8);
        pv1 = *(const short8*)(Vs + ((size_t)b * Ssz + 32 + srow) * Dsz + h * DKsz + schk * 8);
        pidx = *(const u32x4*)(idxb + ((size_t)(b * Ssz + qt * 64 + irow)) * Ssz + ichk * 16);
    }

    for (int it = 0; it < 16; it++) {
        __syncthreads();  // prior-iter LDS reads done + first-iter qe visibility
        // K tile: vector writes, stride 72
        *(short8*)&Klds[(srow)      * 72 + schk * 8] = pk0;
        *(short8*)&Klds[(32 + srow) * 72 + schk * 8] = pk1;
        // V transposed, XOR-swizzled: element (d, s) at [d*72 + (s ^ ((d>>3)<<3))]
        {
            const int ssw0 = srow        ^ (schk << 3);
            const int ssw1 = (32 + srow) ^ (schk << 3);
#pragma unroll
            for (int i = 0; i < 8; i++) {
                Vtlds[(schk * 8 + i) * 72 + ssw0] = (unsigned short)pv0[i];
                Vtlds[(schk * 8 + i) * 72 + ssw1] = (unsigned short)pv1[i];
            }
        }
        *(u32x4*)&Ilds[irow * IPAD + ichk * 16] = pidx;
        __syncthreads();

        // prefetch it+1 (flies during compute below)
        if (it + 1 < 16) {
            const size_t kb = ((size_t)b * Ssz + (it + 1) * 64) * Dsz + h * DKsz;
            pk0 = *(const short8*)(Ks + kb + (size_t)srow * Dsz + schk * 8);
            pk1 = *(const short8*)(Ks + kb + (size_t)(32 + srow) * Dsz + schk * 8);
            pv0 = *(const short8*)(Vs + kb + (size_t)srow * Dsz + schk * 8);
            pv1 = *(const short8*)(Vs + kb + (size_t)(32 + srow) * Dsz + schk * 8);
            pidx = *(const u32x4*)(idxb + ((size_t)(b * Ssz + qt * 64 + irow)) * Ssz + (it + 1) * 64 + ichk * 16);
        }

        // S = Q K^T via MFMA
        f32x4 sf[4];
#pragma unroll
        for (int j = 0; j < 4; j++) sf[j] = (f32x4)0.0f;
#pragma unroll
        for (int st = 0; st < 2; st++) {
#pragma unroll
            for (int j = 0; j < 4; j++) {
                short8 kb2 = *(const short8*)&Klds[(j * 16 + l15) * 72 + st * 32 + quad * 8];
                sf[j] = __builtin_amdgcn_mfma_f32_16x16x32_bf16(qfrag[st], kb2, sf[j], 0, 0, 0);
            }
        }

        // bias via precomputed idx
        float sv[4][4];
#pragma unroll
        for (int r = 0; r < 4; r++) {
            const int m = wave * 16 + quad * 4 + r;
#pragma unroll
            for (int j = 0; j < 4; j++) {
                const int n = j * 16 + l15;
                const int idx = Ilds[m * IPAD + n];
                sv[r][j] = (sf[j][r] + qe[m * NUMEMB + idx]) * 0.125f;
            }
        }

        // online softmax per row
        float alpha[4];
#pragma unroll
        for (int r = 0; r < 4; r++) {
            float vmax = sv[r][0];
#pragma unroll
            for (int j = 1; j < 4; j++) vmax = fmaxf(vmax, sv[r][j]);
#pragma unroll
            for (int off = 1; off < 16; off <<= 1) vmax = fmaxf(vmax, __shfl_xor(vmax, off, 16));
            const float mnew = fmaxf(m_run[r], vmax);
            alpha[r] = __expf(m_run[r] - mnew);
            m_run[r] = mnew;
            float psum = 0.f;
#pragma unroll
            for (int j = 0; j < 4; j++) {
                const float p = __expf(sv[r][j] - mnew);
                sv[r][j] = p;
                psum += p;
            }
#pragma unroll
            for (int off = 1; off < 16; off <<= 1) psum += __shfl_xor(psum, off, 16);
            l_run[r] = l_run[r] * alpha[r] + psum;
        }
#pragma unroll
        for (int j = 0; j < 4; j++) {
            f32x4 o = oacc[j];
#pragma unroll
            for (int r = 0; r < 4; r++) o[r] *= alpha[r];
            oacc[j] = o;
        }

        // P (bf16) -> LDS, XOR-swizzled; wave-private rows (no barrier needed)
#pragma unroll
        for (int r = 0; r < 4; r++) {
            const int m = wave * 16 + quad * 4 + r;
#pragma unroll
            for (int j = 0; j < 4; j++) {
                const int csw = (j * 16 + l15) ^ (quad << 4);
                Plds[m * 72 + csw] = f2bf_bits(sv[r][j]);
            }
        }

        // O += P @ V via MFMA
#pragma unroll
        for (int st = 0; st < 2; st++) {
            const int prow = wave * 16 + l15;
            const int pcsw = (st * 32 + quad * 8) ^ ((l15 >> 2) << 4);
            short8 pf = *(const short8*)&Plds[prow * 72 + pcsw];
#pragma unroll
            for (int j = 0; j < 4; j++) {
                const int d = j * 16 + l15;
                const int vsw = (st * 32 + quad * 8) ^ (((d >> 3) & 7) << 3);
                short8 vb = *(const short8*)&Vtlds[d * 72 + vsw];
                oacc[j] = __builtin_amdgcn_mfma_f32_16x16x32_bf16(pf, vb, oacc[j], 0, 0, 0);
            }
        }
    }

    __syncthreads();  // all Q reads of this block's region done before overwrite

#pragma unroll
    for (int r = 0; r < 4; r++) {
        const float inv = 1.0f / l_run[r];
        const int m = qt * 64 + wave * 16 + quad * 4 + r;
#pragma unroll
        for (int j = 0; j < 4; j++) {
            const int n = h * DKsz + j * 16 + l15;
            const float val = oacc[j][r] * inv;
            const size_t oidx = ((size_t)b * Ssz + m) * Dsz + n;
            if constexpr (QB) ((__hip_bfloat16*)out)[oidx] = __float2bfloat16(val);
            else              ((float*)out)[oidx] = val;
        }
    }
}

__global__ __launch_bounds__(256) void attn_kernel(
    const void* Qw, const short* __restrict__ Ks, const short* __restrict__ Vs,
    const unsigned char* __restrict__ idxb, const float* __restrict__ embf, void* out,
    const int* __restrict__ flags)
{
    __shared__ __align__(16) unsigned short Klds[64 * 72];
    __shared__ __align__(16) unsigned short Vtlds[64 * 72];
    __shared__ __align__(16) unsigned short Plds[64 * 72];
    __shared__ __align__(16) float qe[64 * NUMEMB];
    __shared__ __align__(16) unsigned char Ilds[64 * IPAD];

    if (flags[0] != 0)
        attn_body<true >(Qw, Ks, Vs, idxb, embf, out, Klds, Vtlds, Plds, qe, Ilds);
    else
        attn_body<false>(Qw, Ks, Vs, idxb, embf, out, Klds, Vtlds, Plds, qe, Ilds);
}

extern "C" void kernel_launch(void* const* d_in, const int* in_sizes, int n_in,
                              void* d_out, int out_size, void* d_ws, size_t ws_size,
                              hipStream_t stream) {
    const void* query = d_in[0];
    const void* key   = d_in[1];
    const void* value = d_in[2];
    const void* tpos  = d_in[3];
    const void* Wq    = d_in[4];
    const void* bq    = d_in[5];
    const void* Wk    = d_in[6];
    const void* bk    = d_in[7];
    const void* Wv    = d_in[8];
    const void* bv    = d_in[9];
    const void* emb   = d_in[10];

    int*           flags = (int*)d_ws;
    float*         posf  = (float*)((char*)d_ws + POSF_OFF);
    float*         embf  = (float*)((char*)d_ws + EMBF_OFF);
    unsigned char* idxb  = (unsigned char*)d_ws + IDX_OFF;
    void*          Kw    = (char*)d_ws + K_OFF;
    void*          Vw    = (char*)d_ws + V_OFF;
    void*          Qw    = d_out;   // Q staged in d_out

    detect_kernel<<<4, 64, 0, stream>>>(
        (const unsigned int*)query, (const unsigned int*)tpos,
        (const unsigned int*)Wq, (const unsigned int*)emb, flags);

    prep_kernel<<<4, 256, 0, stream>>>(tpos, emb, flags, posf, embf);

    idx_kernel<<<dim3(16, 16, Bsz), 256, 0, stream>>>(posf, idxb);

    proj_kernel<<<dim3(64, 6, 3), 256, 0, stream>>>(
        query, key, value, Wq, bq, Wk, bk, Wv, bv, Qw, Kw, Vw, flags);

    attn_kernel<<<dim3(16, Hn, Bsz), 256, 0, stream>>>(
        Qw, (const short*)Kw, (const short*)Vw, idxb, embf, d_out, flags);
}

// Round 7
// 229.674 us; speedup vs baseline: 2.0128x; 1.0508x over previous
//
#include <hip/hip_runtime.h>
#include <hip/hip_bf16.h>

#define Bsz 4
#define Ssz 1024
#define Dsz 768
#define Hn 12
#define DKsz 64
#define NUMEMB 10

// d_ws layout (bytes)
#define POSF_OFF 64
#define EMBF_OFF 32832          // 64 + 8192*4
#define IDX_OFF  35392          // EMBF_OFF + 640*4
#define K_OFF    4229696        // IDX_OFF + 4*1024*1024
#define V_OFF    10521152       // K_OFF + 4*1024*768*2

// proj GEMM tile config: 64(M) x 128(N), grid (64,6,3) = 1152 blocks
#define BM 64
#define BN 128
#define BK 32
#define LPAD 40                 // LDS row stride (elems): 32 + 8 pad

#define IPAD 80                 // idx tile row stride (bytes), 16B-aligned

typedef __attribute__((ext_vector_type(8))) short short8;
typedef __attribute__((ext_vector_type(8))) float float8;
typedef __attribute__((ext_vector_type(4))) float f32x4;
typedef __attribute__((ext_vector_type(4))) unsigned int u32x4;

__device__ __forceinline__ float bfbits2f(short u) {
    union { unsigned int i; float f; } v;
    v.i = ((unsigned int)(unsigned short)u) << 16;
    return v.f;
}
__device__ __forceinline__ unsigned short f2bf_bits(float f) {
    __hip_bfloat16 h = __float2bfloat16(f);
    return *reinterpret_cast<unsigned short*>(&h);
}

// DPP lane permute within 16-lane rows (VALU pipe — keeps reductions off LDS)
template<int CTRL>
__device__ __forceinline__ float dppf(float x) {
    int xi = __float_as_int(x);
    int r = __builtin_amdgcn_update_dpp(xi, xi, CTRL, 0xF, 0xF, true);
    return __int_as_float(r);
}
// full 16-lane reduction: quad butterfly (xor1, xor2) then row_ror:4, row_ror:8
__device__ __forceinline__ float red_max16(float v) {
    v = fmaxf(v, dppf<0xB1>(v));    // quad_perm [1,0,3,2]  (xor 1)
    v = fmaxf(v, dppf<0x4E>(v));    // quad_perm [2,3,0,1]  (xor 2)
    v = fmaxf(v, dppf<0x124>(v));   // row_ror:4
    v = fmaxf(v, dppf<0x128>(v));   // row_ror:8
    return v;
}
__device__ __forceinline__ float red_sum16(float v) {
    v += dppf<0xB1>(v);
    v += dppf<0x4E>(v);
    v += dppf<0x124>(v);
    v += dppf<0x128>(v);
    return v;
}

// dtype-dispatched loads: idx is an ELEMENT index (same for both dtypes)
template<bool BF16>
__device__ __forceinline__ float loadf(const void* base, size_t idx) {
    if constexpr (BF16) return __bfloat162float(((const __hip_bfloat16*)base)[idx]);
    else return ((const float*)base)[idx];
}
template<bool BF16>
__device__ __forceinline__ short8 load8bf(const void* base, size_t idx) {
    if constexpr (BF16) {
        return *(const short8*)((const short*)base + idx);
    } else {
        float8 f = *(const float8*)((const float*)base + idx);
        short8 r;
#pragma unroll
        for (int i = 0; i < 8; i++) r[i] = (short)f2bf_bits(f[i]);
        return r;
    }
}

// ---------------- dtype detector ------------------------------------------
__global__ __launch_bounds__(64) void detect_kernel(
    const unsigned int* __restrict__ q, const unsigned int* __restrict__ p,
    const unsigned int* __restrict__ w, const unsigned int* __restrict__ e,
    int* __restrict__ flags)
{
    const int which = blockIdx.x;
    const unsigned int* ptr = (which == 0) ? q : ((which == 1) ? p : ((which == 2) ? w : e));
    const int n = (which == 3) ? 320 : ((which == 1) ? 4096 : 1024);
    int cnt = 0;
    for (int i = threadIdx.x; i < n; i += 64) {
        const unsigned int ex = (ptr[i] >> 7) & 0xFF;
        cnt += (ex >= 110 && ex <= 145) ? 1 : 0;
    }
#pragma unroll
    for (int off = 1; off < 64; off <<= 1) cnt += __shfl_xor(cnt, off, 64);
    if (threadIdx.x == 0) flags[which] = (2 * cnt > n) ? 1 : 0;
}

// canonicalize pos and emb to fp32 scratch (exact conversion either way)
__global__ __launch_bounds__(256) void prep_kernel(
    const void* __restrict__ pos, const void* __restrict__ emb,
    const int* __restrict__ flags, float* __restrict__ posf, float* __restrict__ embf)
{
    const bool pb = flags[1] != 0, eb = flags[3] != 0;
    const int t0 = blockIdx.x * 256 + threadIdx.x;
    for (int i = t0; i < Bsz * Ssz * 2; i += 1024)
        posf[i] = pb ? loadf<true>(pos, i) : loadf<false>(pos, i);
    for (int i = t0; i < NUMEMB * DKsz; i += 1024)
        embf[i] = eb ? loadf<true>(emb, i) : loadf<false>(emb, i);
}

// ---------------- idx precompute: idx[b][i][j], uint8 ----------------------
// Exact fp32 op chain matching numpy. NOTE: dist is exactly symmetric in fp
// ((a-b)^2 == (b-a)^2 under RN), so idx[b][i][j] == idx[b][j][i] bitwise —
// the matrix is its own transpose and attn may read k-rows directly.
__global__ __launch_bounds__(256) void idx_kernel(
    const float* __restrict__ posf, unsigned char* __restrict__ idxb)
{
    const int kt = blockIdx.x, qt = blockIdx.y, b = blockIdx.z;
    const int t = threadIdx.x;
    const int r = t >> 2, cc = t & 3;
    const int q = qt * 64 + r;
    const float qx = posf[((size_t)b * Ssz + q) * 2];
    const float qy = posf[((size_t)b * Ssz + q) * 2 + 1];
    const float MAXD = 141421.35623730951f;  // fp32(100000*sqrt(2))
    const int k0 = kt * 64 + cc * 16;
    unsigned int w[4];
#pragma unroll
    for (int g = 0; g < 4; g++) {
        unsigned int acc = 0;
#pragma unroll
        for (int u = 0; u < 4; u++) {
            const int k = k0 + g * 4 + u;
            const float kx = posf[((size_t)b * Ssz + k) * 2];
            const float ky = posf[((size_t)b * Ssz + k) * 2 + 1];
            const float dx = __fsub_rn(qx, kx);
            const float dy = __fsub_rn(qy, ky);
            const float ss = __fadd_rn(__fmul_rn(dx, dx), __fmul_rn(dy, dy));
            const float dist = __fdiv_rn(sqrtf(ss), MAXD);
            const float d9 = __fmul_rn(dist, 9.0f);
            int idx = (int)rintf(d9);
            idx = idx < 0 ? 0 : (idx > NUMEMB - 1 ? NUMEMB - 1 : idx);
            acc |= ((unsigned int)idx) << (8 * u);
        }
        w[g] = acc;
    }
    u32x4 v; v[0] = w[0]; v[1] = w[1]; v[2] = w[2]; v[3] = w[3];
    *(u32x4*)(idxb + ((size_t)(b * Ssz + q)) * Ssz + k0) = v;
}

// ---------------- Projection GEMM: Y = X @ W^T + b -------------------------
template<bool XB, bool WB>
__device__ __forceinline__ void proj_body(
    const void* X, const void* W, const void* bias, void* Y, bool ybf,
    int bx, int by, short* As, short* Bs)
{
    const int tid  = threadIdx.x;
    const int wave = tid >> 6;
    const int lane = tid & 63;
    const int l15  = lane & 15;
    const int quad = lane >> 4;
    const int wm = wave & 1;
    const int wn = wave >> 1;
    const int m0 = bx * BM;
    const int n0 = by * BN;

    f32x4 acc[2][4];
#pragma unroll
    for (int i = 0; i < 2; i++)
#pragma unroll
        for (int j = 0; j < 4; j++) acc[i][j] = (f32x4)0.0f;

    const int r0 = tid >> 2;     // staging row 0..63
    const int cc = tid & 3;      // staging col-chunk (8 elems)

    // preload kk=0
    short8 pa  = load8bf<XB>(X, (size_t)(m0 + r0)      * Dsz + cc * 8);
    short8 pb0 = load8bf<WB>(W, (size_t)(n0 + r0)      * Dsz + cc * 8);
    short8 pb1 = load8bf<WB>(W, (size_t)(n0 + 64 + r0) * Dsz + cc * 8);

    for (int kk = 0; kk < Dsz; kk += BK) {
        __syncthreads();   // prior iter's frag reads done
        *(short8*)&As[(r0)      * LPAD + cc * 8] = pa;
        *(short8*)&Bs[(r0)      * LPAD + cc * 8] = pb0;
        *(short8*)&Bs[(64 + r0) * LPAD + cc * 8] = pb1;
        __syncthreads();

        if (kk + BK < Dsz) {   // prefetch next tile; flies during MFMA below
            pa  = load8bf<XB>(X, (size_t)(m0 + r0)      * Dsz + kk + BK + cc * 8);
            pb0 = load8bf<WB>(W, (size_t)(n0 + r0)      * Dsz + kk + BK + cc * 8);
            pb1 = load8bf<WB>(W, (size_t)(n0 + 64 + r0) * Dsz + kk + BK + cc * 8);
        }

        short8 af[2], bf[4];
#pragma unroll
        for (int i = 0; i < 2; i++)
            af[i] = *(const short8*)&As[(wm * 32 + i * 16 + l15) * LPAD + quad * 8];
#pragma unroll
        for (int j = 0; j < 4; j++)
            bf[j] = *(const short8*)&Bs[(wn * 64 + j * 16 + l15) * LPAD + quad * 8];
#pragma unroll
        for (int i = 0; i < 2; i++)
#pragma unroll
            for (int j = 0; j < 4; j++)
                acc[i][j] = __builtin_amdgcn_mfma_f32_16x16x32_bf16(af[i], bf[j], acc[i][j], 0, 0, 0);
    }

#pragma unroll
    for (int j = 0; j < 4; j++) {
        const int n = n0 + wn * 64 + j * 16 + l15;
        const float bv_ = loadf<WB>(bias, n);
#pragma unroll
        for (int i = 0; i < 2; i++) {
#pragma unroll
            for (int r = 0; r < 4; r++) {
                const int m = m0 + wm * 32 + i * 16 + quad * 4 + r;
                const float val = acc[i][j][r] + bv_;
                if (ybf) ((__hip_bfloat16*)Y)[(size_t)m * Dsz + n] = __float2bfloat16(val);
                else     ((float*)Y)[(size_t)m * Dsz + n] = val;
            }
        }
    }
}

__global__ __launch_bounds__(256) void proj_kernel(
    const void* X0, const void* X1, const void* X2,
    const void* Wq, const void* bq, const void* Wk, const void* bk,
    const void* Wv, const void* bv,
    void* Qw, void* Kw, void* Vw, const int* __restrict__ flags)
{
    __shared__ __align__(16) short As[BM * LPAD];
    __shared__ __align__(16) short Bs[BN * LPAD];
    const int z = blockIdx.z;
    const void* X = (z == 0) ? X0 : ((z == 1) ? X1 : X2);
    const void* W = (z == 0) ? Wq : ((z == 1) ? Wk : Wv);
    const void* B = (z == 0) ? bq : ((z == 1) ? bk : bv);
    void* Y = (z == 0) ? Qw : ((z == 1) ? Kw : Vw);
    const bool xb = flags[0] != 0, wb = flags[2] != 0;
    const bool ybf = xb || (z != 0);
    if (xb) { if (wb) proj_body<true , true >(X, W, B, Y, ybf, blockIdx.x, blockIdx.y, As, Bs);
              else    proj_body<true , false>(X, W, B, Y, ybf, blockIdx.x, blockIdx.y, As, Bs); }
    else    { if (wb) proj_body<false, true >(X, W, B, Y, ybf, blockIdx.x, blockIdx.y, As, Bs);
              else    proj_body<false, false>(X, W, B, Y, ybf, blockIdx.x, blockIdx.y, As, Bs); }
}

// ---------------- Flash attention with distance-aware key bias --------------
template<bool QB>
__device__ __forceinline__ void attn_body(
    const void* Qw, const short* __restrict__ Ks, const short* __restrict__ Vs,
    const unsigned char* __restrict__ idxb, const float* __restrict__ embf, void* out,
    unsigned short* Klds, unsigned short* Vtlds, unsigned short* Plds,
    float* qe, unsigned char* Ilds)
{
    const int qt = blockIdx.x, h = blockIdx.y, b = blockIdx.z;
    const int tid  = threadIdx.x;
    const int wave = tid >> 6;
    const int lane = tid & 63;
    const int l15  = lane & 15;
    const int quad = lane >> 4;

    // qe[row][e] = sum_d Q[b, qrow, h*64+d] * emb[e][d]
    for (int p = tid; p < 64 * NUMEMB; p += 256) {
        const int row = p / NUMEMB, e = p - row * NUMEMB;
        const size_t qoff = ((size_t)b * Ssz + qt * 64 + row) * Dsz + h * DKsz;
        float s = 0.f;
#pragma unroll
        for (int c = 0; c < 8; c++) {
            short8 qv = load8bf<QB>(Qw, qoff + c * 8);
            const float* er = embf + e * DKsz + c * 8;
#pragma unroll
            for (int i = 0; i < 8; i++) s += bfbits2f(qv[i]) * er[i];
        }
        qe[p] = s;
    }

    // Q fragments (A-layout): row = l15, k = quad*8 + j
    short8 qfrag[2];
    {
        const size_t qbase = ((size_t)b * Ssz + qt * 64 + wave * 16 + l15) * Dsz + h * DKsz;
        qfrag[0] = load8bf<QB>(Qw, qbase + quad * 8);
        qfrag[1] = load8bf<QB>(Qw, qbase + 32 + quad * 8);
    }

    float m_run[4], l_run[4];
    f32x4 oacc[4];
#pragma unroll
    for (int r = 0; r < 4; r++) { m_run[r] = -1e30f; l_run[r] = 0.f; }
#pragma unroll
    for (int j = 0; j < 4; j++) oacc[j] = (f32x4)0.0f;

    // staging lane mappings
    const int srow = tid >> 3, schk = tid & 7;      // K: rows 0..31(+32), chunk 0..7
    const int vp   = tid >> 3;                      // V: row-pair 0..31 (rows 2p,2p+1)
    const int irow = tid >> 2, ichk = tid & 3;      // idx: k-row 0..63, chunk 0..3

    // preload it=0 into registers
    short8 pk0, pk1, pv0, pv1;
    u32x4 pidx;
    {
        pk0 = *(const short8*)(Ks + ((size_t)b * Ssz + srow)       * Dsz + h * DKsz + schk * 8);
        pk1 = *(const short8*)(Ks + ((size_t)b * Ssz + 32 + srow)  * Dsz + h * DKsz + schk * 8);
        pv0 = *(const short8*)(Vs + ((size_t)b * Ssz + 2 * vp)     * Dsz + h * DKsz + schk * 8);
        pv1 = *(const short8*)(Vs + ((size_t)b * Ssz + 2 * vp + 1) * Dsz + h * DKsz + schk * 8);
        // idx is symmetric: row = key index, cols = this block's 64 q's
        pidx = *(const u32x4*)(idxb + ((size_t)(b * Ssz + irow)) * Ssz + qt * 64 + ichk * 16);
    }

    for (int it = 0; it < 16; it++) {
        __syncthreads();  // prior-iter LDS reads done + first-iter qe visibility
        // K tile: vector writes, stride 72
        *(short8*)&Klds[(srow)      * 72 + schk * 8] = pk0;
        *(short8*)&Klds[(32 + srow) * 72 + schk * 8] = pk1;
        // V transposed, XOR-swizzled, paired-row b32 writes:
        // dword at [d*72 + ((2p) ^ (schk<<3))] = {V[2p][d], V[2p+1][d]}
        {
            const int ssw = (2 * vp) ^ (schk << 3);
#pragma unroll
            for (int i = 0; i < 8; i++) {
                const unsigned int dw = (unsigned int)(unsigned short)pv0[i]
                                      | ((unsigned int)(unsigned short)pv1[i] << 16);
                *(unsigned int*)&Vtlds[(schk * 8 + i) * 72 + ssw] = dw;
            }
        }
        // idx tile: k-rows, q-cols (transposed-by-symmetry), stride IPAD
        *(u32x4*)&Ilds[irow * IPAD + ichk * 16] = pidx;
        __syncthreads();

        // prefetch it+1 (flies during compute below)
        if (it + 1 < 16) {
            const size_t kb = ((size_t)b * Ssz + (it + 1) * 64) * Dsz + h * DKsz;
            pk0 = *(const short8*)(Ks + kb + (size_t)srow * Dsz + schk * 8);
            pk1 = *(const short8*)(Ks + kb + (size_t)(32 + srow) * Dsz + schk * 8);
            pv0 = *(const short8*)(Vs + kb + (size_t)(2 * vp) * Dsz + schk * 8);
            pv1 = *(const short8*)(Vs + kb + (size_t)(2 * vp + 1) * Dsz + schk * 8);
            pidx = *(const u32x4*)(idxb + ((size_t)(b * Ssz + (it + 1) * 64 + irow)) * Ssz + qt * 64 + ichk * 16);
        }

        // S = Q K^T via MFMA
        f32x4 sf[4];
#pragma unroll
        for (int j = 0; j < 4; j++) sf[j] = (f32x4)0.0f;
#pragma unroll
        for (int st = 0; st < 2; st++) {
#pragma unroll
            for (int j = 0; j < 4; j++) {
                short8 kb2 = *(const short8*)&Klds[(j * 16 + l15) * 72 + st * 32 + quad * 8];
                sf[j] = __builtin_amdgcn_mfma_f32_16x16x32_bf16(qfrag[st], kb2, sf[j], 0, 0, 0);
            }
        }

        // bias via idx tile: one b32 per j covers all 4 r's (k-row = j*16+l15,
        // q-col = wave*16 + quad*4 + r)
        float sv[4][4];
#pragma unroll
        for (int j = 0; j < 4; j++) {
            const unsigned int iw = *(const unsigned int*)&Ilds[(j * 16 + l15) * IPAD + wave * 16 + quad * 4];
#pragma unroll
            for (int r = 0; r < 4; r++) {
                const int m = wave * 16 + quad * 4 + r;
                const int idx = (iw >> (8 * r)) & 0xFF;
                sv[r][j] = (sf[j][r] + qe[m * NUMEMB + idx]) * 0.125f;
            }
        }

        // online softmax per row — DPP reductions (VALU pipe, no LDS traffic)
        float alpha[4];
#pragma unroll
        for (int r = 0; r < 4; r++) {
            float vmax = fmaxf(fmaxf(sv[r][0], sv[r][1]), fmaxf(sv[r][2], sv[r][3]));
            vmax = red_max16(vmax);
            const float mnew = fmaxf(m_run[r], vmax);
            alpha[r] = __expf(m_run[r] - mnew);
            m_run[r] = mnew;
            float psum = 0.f;
#pragma unroll
            for (int j = 0; j < 4; j++) {
                const float p = __expf(sv[r][j] - mnew);
                sv[r][j] = p;
                psum += p;
            }
            psum = red_sum16(psum);
            l_run[r] = l_run[r] * alpha[r] + psum;
        }
#pragma unroll
        for (int j = 0; j < 4; j++) {
            f32x4 o = oacc[j];
#pragma unroll
            for (int r = 0; r < 4; r++) o[r] *= alpha[r];
            oacc[j] = o;
        }

        // P (bf16) -> LDS, XOR-swizzled; wave-private rows (no barrier needed)
#pragma unroll
        for (int r = 0; r < 4; r++) {
            const int m = wave * 16 + quad * 4 + r;
#pragma unroll
            for (int j = 0; j < 4; j++) {
                const int csw = (j * 16 + l15) ^ (quad << 4);
                Plds[m * 72 + csw] = f2bf_bits(sv[r][j]);
            }
        }

        // O += P @ V via MFMA
#pragma unroll
        for (int st = 0; st < 2; st++) {
            const int prow = wave * 16 + l15;
            const int pcsw = (st * 32 + quad * 8) ^ ((l15 >> 2) << 4);
            short8 pf = *(const short8*)&Plds[prow * 72 + pcsw];
#pragma unroll
            for (int j = 0; j < 4; j++) {
                const int d = j * 16 + l15;
                const int vsw = (st * 32 + quad * 8) ^ (((d >> 3) & 7) << 3);
                short8 vb = *(const short8*)&Vtlds[d * 72 + vsw];
                oacc[j] = __builtin_amdgcn_mfma_f32_16x16x32_bf16(pf, vb, oacc[j], 0, 0, 0);
            }
        }
    }

    __syncthreads();  // all Q reads of this block's region done before overwrite

#pragma unroll
    for (int r = 0; r < 4; r++) {
        const float inv = 1.0f / l_run[r];
        const int m = qt * 64 + wave * 16 + quad * 4 + r;
#pragma unroll
        for (int j = 0; j < 4; j++) {
            const int n = h * DKsz + j * 16 + l15;
            const float val = oacc[j][r] * inv;
            const size_t oidx = ((size_t)b * Ssz + m) * Dsz + n;
            if constexpr (QB) ((__hip_bfloat16*)out)[oidx] = __float2bfloat16(val);
            else              ((float*)out)[oidx] = val;
        }
    }
}

__global__ __launch_bounds__(256) void attn_kernel(
    const void* Qw, const short* __restrict__ Ks, const short* __restrict__ Vs,
    const unsigned char* __restrict__ idxb, const float* __restrict__ embf, void* out,
    const int* __restrict__ flags)
{
    __shared__ __align__(16) unsigned short Klds[64 * 72];
    __shared__ __align__(16) unsigned short Vtlds[64 * 72];
    __shared__ __align__(16) unsigned short Plds[64 * 72];
    __shared__ __align__(16) float qe[64 * NUMEMB];
    __shared__ __align__(16) unsigned char Ilds[64 * IPAD];

    if (flags[0] != 0)
        attn_body<true >(Qw, Ks, Vs, idxb, embf, out, Klds, Vtlds, Plds, qe, Ilds);
    else
        attn_body<false>(Qw, Ks, Vs, idxb, embf, out, Klds, Vtlds, Plds, qe, Ilds);
}

extern "C" void kernel_launch(void* const* d_in, const int* in_sizes, int n_in,
                              void* d_out, int out_size, void* d_ws, size_t ws_size,
                              hipStream_t stream) {
    const void* query = d_in[0];
    const void* key   = d_in[1];
    const void* value = d_in[2];
    const void* tpos  = d_in[3];
    const void* Wq    = d_in[4];
    const void* bq    = d_in[5];
    const void* Wk    = d_in[6];
    const void* bk    = d_in[7];
    const void* Wv    = d_in[8];
    const void* bv    = d_in[9];
    const void* emb   = d_in[10];

    int*           flags = (int*)d_ws;
    float*         posf  = (float*)((char*)d_ws + POSF_OFF);
    float*         embf  = (float*)((char*)d_ws + EMBF_OFF);
    unsigned char* idxb  = (unsigned char*)d_ws + IDX_OFF;
    void*          Kw    = (char*)d_ws + K_OFF;
    void*          Vw    = (char*)d_ws + V_OFF;
    void*          Qw    = d_out;   // Q staged in d_out

    detect_kernel<<<4, 64, 0, stream>>>(
        (const unsigned int*)query, (const unsigned int*)tpos,
        (const unsigned int*)Wq, (const unsigned int*)emb, flags);

    prep_kernel<<<4, 256, 0, stream>>>(tpos, emb, flags, posf, embf);

    idx_kernel<<<dim3(16, 16, Bsz), 256, 0, stream>>>(posf, idxb);

    proj_kernel<<<dim3(64, 6, 3), 256, 0, stream>>>(
        query, key, value, Wq, bq, Wk, bk, Wv, bv, Qw, Kw, Vw, flags);

    attn_kernel<<<dim3(16, Hn, Bsz), 256, 0, stream>>>(
        Qw, (const short*)Kw, (const short*)Vw, idxb, embf, d_out, flags);
}

// Round 8
// 221.018 us; speedup vs baseline: 2.0916x; 1.0392x over previous
//
#include <hip/hip_runtime.h>
#include <hip/hip_bf16.h>

#define Bsz 4
#define Ssz 1024
#define Dsz 768
#define Hn 12
#define DKsz 64
#define NUMEMB 10

// d_ws layout (bytes)
#define IDX_OFF 64
#define K_OFF   4194368          // IDX_OFF + 4*1024*1024
#define V_OFF   10485824         // K_OFF + 4*1024*768*2
#define WBF_OFF 16777280         // V_OFF + 4*1024*768*2
#define XBF_OFF 20316224         // WBF_OFF + 3*768*768*2
#define WS_TIER_B 20316224ULL    // enough for Wbf
#define WS_TIER_A 39190592ULL    // enough for Wbf + Xbf

#define NXz 3145728              // elems per X tensor (4*1024*768)
#define NWz 589824               // elems per W tensor (768*768)

#define IPAD 80                  // idx tile row stride (bytes)

typedef __attribute__((ext_vector_type(8))) short short8;
typedef __attribute__((ext_vector_type(8))) float float8;
typedef __attribute__((ext_vector_type(4))) float f32x4;
typedef __attribute__((ext_vector_type(4))) unsigned int u32x4;

__device__ __forceinline__ float bfbits2f(short u) {
    union { unsigned int i; float f; } v;
    v.i = ((unsigned int)(unsigned short)u) << 16;
    return v.f;
}
__device__ __forceinline__ unsigned short f2bf_bits(float f) {
    __hip_bfloat16 h = __float2bfloat16(f);
    return *reinterpret_cast<unsigned short*>(&h);
}

// DPP lane permute within 16-lane rows (VALU pipe)
template<int CTRL>
__device__ __forceinline__ float dppf(float x) {
    int xi = __float_as_int(x);
    int r = __builtin_amdgcn_update_dpp(xi, xi, CTRL, 0xF, 0xF, true);
    return __int_as_float(r);
}
__device__ __forceinline__ float red_max16(float v) {
    v = fmaxf(v, dppf<0xB1>(v));
    v = fmaxf(v, dppf<0x4E>(v));
    v = fmaxf(v, dppf<0x124>(v));
    v = fmaxf(v, dppf<0x128>(v));
    return v;
}
__device__ __forceinline__ float red_sum16(float v) {
    v += dppf<0xB1>(v);
    v += dppf<0x4E>(v);
    v += dppf<0x124>(v);
    v += dppf<0x128>(v);
    return v;
}

// dtype-dispatched loads: idx is an ELEMENT index
template<bool BF16>
__device__ __forceinline__ float loadf(const void* base, size_t idx) {
    if constexpr (BF16) return __bfloat162float(((const __hip_bfloat16*)base)[idx]);
    else return ((const float*)base)[idx];
}
template<bool BF16>
__device__ __forceinline__ short8 load8bf(const void* base, size_t idx) {
    if constexpr (BF16) {
        return *(const short8*)((const short*)base + idx);
    } else {
        float8 f = *(const float8*)((const float*)base + idx);
        short8 r;
#pragma unroll
        for (int i = 0; i < 8; i++) r[i] = (short)f2bf_bits(f[i]);
        return r;
    }
}
template<bool BF16>
__device__ __forceinline__ float8 load8f(const void* base, size_t idx) {
    if constexpr (BF16) {
        short8 s = *(const short8*)((const short*)base + idx);
        float8 f;
#pragma unroll
        for (int i = 0; i < 8; i++) f[i] = bfbits2f(s[i]);
        return f;
    } else {
        return *(const float8*)((const float*)base + idx);
    }
}

// ---------------- dtype detector ------------------------------------------
__global__ __launch_bounds__(64) void detect_kernel(
    const unsigned int* __restrict__ q, const unsigned int* __restrict__ p,
    const unsigned int* __restrict__ w, const unsigned int* __restrict__ e,
    int* __restrict__ flags)
{
    const int which = blockIdx.x;
    const unsigned int* ptr = (which == 0) ? q : ((which == 1) ? p : ((which == 2) ? w : e));
    const int n = (which == 3) ? 320 : ((which == 1) ? 4096 : 1024);
    int cnt = 0;
    for (int i = threadIdx.x; i < n; i += 64) {
        const unsigned int ex = (ptr[i] >> 7) & 0xFF;
        cnt += (ex >= 110 && ex <= 145) ? 1 : 0;
    }
#pragma unroll
    for (int off = 1; off < 64; off <<= 1) cnt += __shfl_xor(cnt, off, 64);
    if (threadIdx.x == 0) flags[which] = (2 * cnt > n) ? 1 : 0;
}

// ---------------- one-time bf16 canonicalization of X / W ------------------
__global__ __launch_bounds__(256) void conv_kernel(
    const void* __restrict__ X0, const void* __restrict__ X1, const void* __restrict__ X2,
    const void* __restrict__ W0, const void* __restrict__ W1, const void* __restrict__ W2,
    const int* __restrict__ flags, short* __restrict__ Xbf, short* __restrict__ Wbf,
    int doX)
{
    const long t = (long)blockIdx.x * 256 + threadIdx.x;
    const bool xb = flags[0] != 0, wb = flags[2] != 0;
    if (doX) {
        const long i8 = t * 8;
        if (i8 < (long)3 * NXz) {
            const int z = (int)(i8 / NXz);
            const long off = i8 - (long)z * NXz;
            const void* X = (z == 0) ? X0 : ((z == 1) ? X1 : X2);
            short8 v = xb ? load8bf<true>(X, off) : load8bf<false>(X, off);
            *(short8*)(Xbf + i8) = v;
        } else {
            const long j = i8 - (long)3 * NXz;
            const int z = (int)(j / NWz);
            const long off = j - (long)z * NWz;
            const void* W = (z == 0) ? W0 : ((z == 1) ? W1 : W2);
            short8 v = wb ? load8bf<true>(W, off) : load8bf<false>(W, off);
            *(short8*)(Wbf + j) = v;
        }
    } else {
        const long j = t * 8;
        const int z = (int)(j / NWz);
        const long off = j - (long)z * NWz;
        const void* W = (z == 0) ? W0 : ((z == 1) ? W1 : W2);
        short8 v = wb ? load8bf<true>(W, off) : load8bf<false>(W, off);
        *(short8*)(Wbf + j) = v;
    }
}

// ---------------- idx precompute: idx[b][i][j], uint8 ----------------------
// Exact fp32 op chain matching numpy; matrix is bitwise symmetric.
template<bool PB>
__device__ __forceinline__ void idx_body(
    const void* pos, unsigned char* __restrict__ idxb)
{
    const int kt = blockIdx.x, qt = blockIdx.y, b = blockIdx.z;
    const int t = threadIdx.x;
    const int r = t >> 2, cc = t & 3;
    const int q = qt * 64 + r;
    const float qx = loadf<PB>(pos, ((size_t)b * Ssz + q) * 2);
    const float qy = loadf<PB>(pos, ((size_t)b * Ssz + q) * 2 + 1);
    const float MAXD = 141421.35623730951f;  // fp32(100000*sqrt(2))
    const int k0 = kt * 64 + cc * 16;
    unsigned int w[4];
#pragma unroll
    for (int g = 0; g < 4; g++) {
        unsigned int acc = 0;
#pragma unroll
        for (int u = 0; u < 4; u++) {
            const int k = k0 + g * 4 + u;
            const float kx = loadf<PB>(pos, ((size_t)b * Ssz + k) * 2);
            const float ky = loadf<PB>(pos, ((size_t)b * Ssz + k) * 2 + 1);
            const float dx = __fsub_rn(qx, kx);
            const float dy = __fsub_rn(qy, ky);
            const float ss = __fadd_rn(__fmul_rn(dx, dx), __fmul_rn(dy, dy));
            const float dist = __fdiv_rn(sqrtf(ss), MAXD);
            const float d9 = __fmul_rn(dist, 9.0f);
            int idx = (int)rintf(d9);
            idx = idx < 0 ? 0 : (idx > NUMEMB - 1 ? NUMEMB - 1 : idx);
            acc |= ((unsigned int)idx) << (8 * u);
        }
        w[g] = acc;
    }
    u32x4 v; v[0] = w[0]; v[1] = w[1]; v[2] = w[2]; v[3] = w[3];
    *(u32x4*)(idxb + ((size_t)(b * Ssz + q)) * Ssz + k0) = v;
}

__global__ __launch_bounds__(256) void idx_kernel(
    const void* pos, const int* __restrict__ flags, unsigned char* __restrict__ idxb)
{
    if (flags[1] != 0) idx_body<true >(pos, idxb);
    else               idx_body<false>(pos, idxb);
}

// ---------------- Projection GEMM: Y = X @ W^T + b -------------------------
// 64x128 tile, BK=64 (12 iters, 24 barriers), reg-prefetch pipelined.
template<bool XB, bool WB>
__device__ __forceinline__ void proj_body(
    const void* X, const void* W, const void* bias, bool biasbf, void* Y, bool ybf,
    int bx, int by, short* As, short* Bs)
{
    const int tid  = threadIdx.x;
    const int wave = tid >> 6;
    const int lane = tid & 63;
    const int l15  = lane & 15;
    const int quad = lane >> 4;
    const int wm = wave & 1;
    const int wn = wave >> 1;
    const int m0 = bx * 64;
    const int n0 = by * 128;

    f32x4 acc[2][4];
#pragma unroll
    for (int i = 0; i < 2; i++)
#pragma unroll
        for (int j = 0; j < 4; j++) acc[i][j] = (f32x4)0.0f;

    const int r0 = tid >> 3;     // staging row 0..31
    const int cc = tid & 7;      // staging col-chunk (8 elems)

    // preload kk=0 (6 chunks: 2 A rows, 4 B rows)
    short8 pa0 = load8bf<XB>(X, (size_t)(m0 + r0)      * Dsz + cc * 8);
    short8 pa1 = load8bf<XB>(X, (size_t)(m0 + 32 + r0) * Dsz + cc * 8);
    short8 pb0 = load8bf<WB>(W, (size_t)(n0 + r0)      * Dsz + cc * 8);
    short8 pb1 = load8bf<WB>(W, (size_t)(n0 + 32 + r0) * Dsz + cc * 8);
    short8 pb2 = load8bf<WB>(W, (size_t)(n0 + 64 + r0) * Dsz + cc * 8);
    short8 pb3 = load8bf<WB>(W, (size_t)(n0 + 96 + r0) * Dsz + cc * 8);

    for (int kk = 0; kk < Dsz; kk += 64) {
        __syncthreads();   // prior iter's frag reads done
        *(short8*)&As[(r0)      * 72 + cc * 8] = pa0;
        *(short8*)&As[(32 + r0) * 72 + cc * 8] = pa1;
        *(short8*)&Bs[(r0)      * 72 + cc * 8] = pb0;
        *(short8*)&Bs[(32 + r0) * 72 + cc * 8] = pb1;
        *(short8*)&Bs[(64 + r0) * 72 + cc * 8] = pb2;
        *(short8*)&Bs[(96 + r0) * 72 + cc * 8] = pb3;
        __syncthreads();

        if (kk + 64 < Dsz) {   // prefetch next tile; flies during MFMA below
            const int k2 = kk + 64 + cc * 8;
            pa0 = load8bf<XB>(X, (size_t)(m0 + r0)      * Dsz + k2);
            pa1 = load8bf<XB>(X, (size_t)(m0 + 32 + r0) * Dsz + k2);
            pb0 = load8bf<WB>(W, (size_t)(n0 + r0)      * Dsz + k2);
            pb1 = load8bf<WB>(W, (size_t)(n0 + 32 + r0) * Dsz + k2);
            pb2 = load8bf<WB>(W, (size_t)(n0 + 64 + r0) * Dsz + k2);
            pb3 = load8bf<WB>(W, (size_t)(n0 + 96 + r0) * Dsz + k2);
        }

#pragma unroll
        for (int st = 0; st < 2; st++) {   // k-order preserved: st0 then st1
            short8 af[2], bf[4];
#pragma unroll
            for (int i = 0; i < 2; i++)
                af[i] = *(const short8*)&As[(wm * 32 + i * 16 + l15) * 72 + st * 32 + quad * 8];
#pragma unroll
            for (int j = 0; j < 4; j++)
                bf[j] = *(const short8*)&Bs[(wn * 64 + j * 16 + l15) * 72 + st * 32 + quad * 8];
#pragma unroll
            for (int i = 0; i < 2; i++)
#pragma unroll
                for (int j = 0; j < 4; j++)
                    acc[i][j] = __builtin_amdgcn_mfma_f32_16x16x32_bf16(af[i], bf[j], acc[i][j], 0, 0, 0);
        }
    }

#pragma unroll
    for (int j = 0; j < 4; j++) {
        const int n = n0 + wn * 64 + j * 16 + l15;
        const float bv_ = biasbf ? loadf<true>(bias, n) : loadf<false>(bias, n);
#pragma unroll
        for (int i = 0; i < 2; i++) {
#pragma unroll
            for (int r = 0; r < 4; r++) {
                const int m = m0 + wm * 32 + i * 16 + quad * 4 + r;
                const float val = acc[i][j][r] + bv_;
                if (ybf) ((__hip_bfloat16*)Y)[(size_t)m * Dsz + n] = __float2bfloat16(val);
                else     ((float*)Y)[(size_t)m * Dsz + n] = val;
            }
        }
    }
}

__global__ __launch_bounds__(256) void proj_kernel(
    const void* X0, const void* X1, const void* X2,
    const void* Wq, const void* bq, const void* Wk, const void* bk,
    const void* Wv, const void* bv,
    void* Qw, void* Kw, void* Vw, const int* __restrict__ flags,
    int fx, int fw)
{
    __shared__ __align__(16) short As[64 * 72];
    __shared__ __align__(16) short Bs[128 * 72];
    const int z = blockIdx.z;
    const void* X = (z == 0) ? X0 : ((z == 1) ? X1 : X2);
    const void* W = (z == 0) ? Wq : ((z == 1) ? Wk : Wv);
    const void* B = (z == 0) ? bq : ((z == 1) ? bk : bv);
    void* Y = (z == 0) ? Qw : ((z == 1) ? Kw : Vw);
    const bool xb = fx || flags[0] != 0;          // data dtype at X pointer
    const bool wb = fw || flags[2] != 0;          // data dtype at W pointer
    const bool biasbf = flags[2] != 0;            // bias is always the RAW tensor
    const bool ybf = (flags[0] != 0) || (z != 0); // Q in input dtype; K/V bf16
    if (xb) { if (wb) proj_body<true , true >(X, W, B, biasbf, Y, ybf, blockIdx.x, blockIdx.y, As, Bs);
              else    proj_body<true , false>(X, W, B, biasbf, Y, ybf, blockIdx.x, blockIdx.y, As, Bs); }
    else    { if (wb) proj_body<false, true >(X, W, B, biasbf, Y, ybf, blockIdx.x, blockIdx.y, As, Bs);
              else    proj_body<false, false>(X, W, B, biasbf, Y, ybf, blockIdx.x, blockIdx.y, As, Bs); }
}

// ---------------- Flash attention with distance-aware key bias --------------
template<bool QB, bool EB>
__device__ __forceinline__ void attn_body(
    const void* Qw, const short* __restrict__ Ks, const short* __restrict__ Vs,
    const unsigned char* __restrict__ idxb, const void* __restrict__ emb, void* out,
    unsigned short* Klds, unsigned short* Vtlds, unsigned short* Plds,
    float* qe, unsigned char* Ilds)
{
    const int qt = blockIdx.x, h = blockIdx.y, b = blockIdx.z;
    const int tid  = threadIdx.x;
    const int wave = tid >> 6;
    const int lane = tid & 63;
    const int l15  = lane & 15;
    const int quad = lane >> 4;

    // qe[row][e] = sum_d Q[b, qrow, h*64+d] * emb[e][d]
    for (int p = tid; p < 64 * NUMEMB; p += 256) {
        const int row = p / NUMEMB, e = p - row * NUMEMB;
        const size_t qoff = ((size_t)b * Ssz + qt * 64 + row) * Dsz + h * DKsz;
        float s = 0.f;
#pragma unroll
        for (int c = 0; c < 8; c++) {
            short8 qv = load8bf<QB>(Qw, qoff + c * 8);
            float8 ef = load8f<EB>(emb, (size_t)e * DKsz + c * 8);
#pragma unroll
            for (int i = 0; i < 8; i++) s += bfbits2f(qv[i]) * ef[i];
        }
        qe[p] = s;
    }

    // Q fragments (A-layout): row = l15, k = quad*8 + j
    short8 qfrag[2];
    {
        const size_t qbase = ((size_t)b * Ssz + qt * 64 + wave * 16 + l15) * Dsz + h * DKsz;
        qfrag[0] = load8bf<QB>(Qw, qbase + quad * 8);
        qfrag[1] = load8bf<QB>(Qw, qbase + 32 + quad * 8);
    }

    float m_run[4], l_run[4];
    f32x4 oacc[4];
#pragma unroll
    for (int r = 0; r < 4; r++) { m_run[r] = -1e30f; l_run[r] = 0.f; }
#pragma unroll
    for (int j = 0; j < 4; j++) oacc[j] = (f32x4)0.0f;

    // staging lane mappings
    const int srow = tid >> 3, schk = tid & 7;
    const int vp   = tid >> 3;
    const int irow = tid >> 2, ichk = tid & 3;

    short8 pk0, pk1, pv0, pv1;
    u32x4 pidx;
    {
        pk0 = *(const short8*)(Ks + ((size_t)b * Ssz + srow)       * Dsz + h * DKsz + schk * 8);
        pk1 = *(const short8*)(Ks + ((size_t)b * Ssz + 32 + srow)  * Dsz + h * DKsz + schk * 8);
        pv0 = *(const short8*)(Vs + ((size_t)b * Ssz + 2 * vp)     * Dsz + h * DKsz + schk * 8);
        pv1 = *(const short8*)(Vs + ((size_t)b * Ssz + 2 * vp + 1) * Dsz + h * DKsz + schk * 8);
        pidx = *(const u32x4*)(idxb + ((size_t)(b * Ssz + irow)) * Ssz + qt * 64 + ichk * 16);
    }

    for (int it = 0; it < 16; it++) {
        __syncthreads();
        *(short8*)&Klds[(srow)      * 72 + schk * 8] = pk0;
        *(short8*)&Klds[(32 + srow) * 72 + schk * 8] = pk1;
        {
            const int ssw = (2 * vp) ^ (schk << 3);
#pragma unroll
            for (int i = 0; i < 8; i++) {
                const unsigned int dw = (unsigned int)(unsigned short)pv0[i]
                                      | ((unsigned int)(unsigned short)pv1[i] << 16);
                *(unsigned int*)&Vtlds[(schk * 8 + i) * 72 + ssw] = dw;
            }
        }
        *(u32x4*)&Ilds[irow * IPAD + ichk * 16] = pidx;
        __syncthreads();

        if (it + 1 < 16) {
            const size_t kb = ((size_t)b * Ssz + (it + 1) * 64) * Dsz + h * DKsz;
            pk0 = *(const short8*)(Ks + kb + (size_t)srow * Dsz + schk * 8);
            pk1 = *(const short8*)(Ks + kb + (size_t)(32 + srow) * Dsz + schk * 8);
            pv0 = *(const short8*)(Vs + kb + (size_t)(2 * vp) * Dsz + schk * 8);
            pv1 = *(const short8*)(Vs + kb + (size_t)(2 * vp + 1) * Dsz + schk * 8);
            pidx = *(const u32x4*)(idxb + ((size_t)(b * Ssz + (it + 1) * 64 + irow)) * Ssz + qt * 64 + ichk * 16);
        }

        // S = Q K^T via MFMA
        f32x4 sf[4];
#pragma unroll
        for (int j = 0; j < 4; j++) sf[j] = (f32x4)0.0f;
#pragma unroll
        for (int st = 0; st < 2; st++) {
#pragma unroll
            for (int j = 0; j < 4; j++) {
                short8 kb2 = *(const short8*)&Klds[(j * 16 + l15) * 72 + st * 32 + quad * 8];
                sf[j] = __builtin_amdgcn_mfma_f32_16x16x32_bf16(qfrag[st], kb2, sf[j], 0, 0, 0);
            }
        }

        // bias via idx tile (symmetric layout: k-row, q-col)
        float sv[4][4];
#pragma unroll
        for (int j = 0; j < 4; j++) {
            const unsigned int iw = *(const unsigned int*)&Ilds[(j * 16 + l15) * IPAD + wave * 16 + quad * 4];
#pragma unroll
            for (int r = 0; r < 4; r++) {
                const int m = wave * 16 + quad * 4 + r;
                const int idx = (iw >> (8 * r)) & 0xFF;
                sv[r][j] = (sf[j][r] + qe[m * NUMEMB + idx]) * 0.125f;
            }
        }

        // online softmax per row — DPP reductions
        float alpha[4];
#pragma unroll
        for (int r = 0; r < 4; r++) {
            float vmax = fmaxf(fmaxf(sv[r][0], sv[r][1]), fmaxf(sv[r][2], sv[r][3]));
            vmax = red_max16(vmax);
            const float mnew = fmaxf(m_run[r], vmax);
            alpha[r] = __expf(m_run[r] - mnew);
            m_run[r] = mnew;
            float psum = 0.f;
#pragma unroll
            for (int j = 0; j < 4; j++) {
                const float p = __expf(sv[r][j] - mnew);
                sv[r][j] = p;
                psum += p;
            }
            psum = red_sum16(psum);
            l_run[r] = l_run[r] * alpha[r] + psum;
        }
#pragma unroll
        for (int j = 0; j < 4; j++) {
            f32x4 o = oacc[j];
#pragma unroll
            for (int r = 0; r < 4; r++) o[r] *= alpha[r];
            oacc[j] = o;
        }

        // P (bf16) -> LDS, XOR-swizzled; wave-private rows
#pragma unroll
        for (int r = 0; r < 4; r++) {
            const int m = wave * 16 + quad * 4 + r;
#pragma unroll
            for (int j = 0; j < 4; j++) {
                const int csw = (j * 16 + l15) ^ (quad << 4);
                Plds[m * 72 + csw] = f2bf_bits(sv[r][j]);
            }
        }

        // O += P @ V via MFMA
#pragma unroll
        for (int st = 0; st < 2; st++) {
            const int prow = wave * 16 + l15;
            const int pcsw = (st * 32 + quad * 8) ^ ((l15 >> 2) << 4);
            short8 pf = *(const short8*)&Plds[prow * 72 + pcsw];
#pragma unroll
            for (int j = 0; j < 4; j++) {
                const int d = j * 16 + l15;
                const int vsw = (st * 32 + quad * 8) ^ (((d >> 3) & 7) << 3);
                short8 vb = *(const short8*)&Vtlds[d * 72 + vsw];
                oacc[j] = __builtin_amdgcn_mfma_f32_16x16x32_bf16(pf, vb, oacc[j], 0, 0, 0);
            }
        }
    }

    __syncthreads();  // all Q reads of this block's region done before overwrite

#pragma unroll
    for (int r = 0; r < 4; r++) {
        const float inv = 1.0f / l_run[r];
        const int m = qt * 64 + wave * 16 + quad * 4 + r;
#pragma unroll
        for (int j = 0; j < 4; j++) {
            const int n = h * DKsz + j * 16 + l15;
            const float val = oacc[j][r] * inv;
            const size_t oidx = ((size_t)b * Ssz + m) * Dsz + n;
            if constexpr (QB) ((__hip_bfloat16*)out)[oidx] = __float2bfloat16(val);
            else              ((float*)out)[oidx] = val;
        }
    }
}

__global__ __launch_bounds__(256) void attn_kernel(
    const void* Qw, const short* __restrict__ Ks, const short* __restrict__ Vs,
    const unsigned char* __restrict__ idxb, const void* __restrict__ emb, void* out,
    const int* __restrict__ flags)
{
    __shared__ __align__(16) unsigned short Klds[64 * 72];
    __shared__ __align__(16) unsigned short Vtlds[64 * 72];
    __shared__ __align__(16) unsigned short Plds[64 * 72];
    __shared__ __align__(16) float qe[64 * NUMEMB];
    __shared__ __align__(16) unsigned char Ilds[64 * IPAD];

    const bool qb = flags[0] != 0, eb = flags[3] != 0;
    if (qb) { if (eb) attn_body<true , true >(Qw, Ks, Vs, idxb, emb, out, Klds, Vtlds, Plds, qe, Ilds);
              else    attn_body<true , false>(Qw, Ks, Vs, idxb, emb, out, Klds, Vtlds, Plds, qe, Ilds); }
    else    { if (eb) attn_body<false, true >(Qw, Ks, Vs, idxb, emb, out, Klds, Vtlds, Plds, qe, Ilds);
              else    attn_body<false, false>(Qw, Ks, Vs, idxb, emb, out, Klds, Vtlds, Plds, qe, Ilds); }
}

extern "C" void kernel_launch(void* const* d_in, const int* in_sizes, int n_in,
                              void* d_out, int out_size, void* d_ws, size_t ws_size,
                              hipStream_t stream) {
    const void* query = d_in[0];
    const void* key   = d_in[1];
    const void* value = d_in[2];
    const void* tpos  = d_in[3];
    const void* Wq    = d_in[4];
    const void* bq    = d_in[5];
    const void* Wk    = d_in[6];
    const void* bk    = d_in[7];
    const void* Wv    = d_in[8];
    const void* bv    = d_in[9];
    const void* emb   = d_in[10];

    int*           flags = (int*)d_ws;
    unsigned char* idxb  = (unsigned char*)d_ws + IDX_OFF;
    void*          Kw    = (char*)d_ws + K_OFF;
    void*          Vw    = (char*)d_ws + V_OFF;
    short*         Wbf   = (short*)((char*)d_ws + WBF_OFF);
    short*         Xbf   = (short*)((char*)d_ws + XBF_OFF);
    void*          Qw    = d_out;   // Q staged in d_out

    const bool tierA = ws_size >= WS_TIER_A;
    const bool tierB = !tierA && ws_size >= WS_TIER_B;

    detect_kernel<<<4, 64, 0, stream>>>(
        (const unsigned int*)query, (const unsigned int*)tpos,
        (const unsigned int*)Wq, (const unsigned int*)emb, flags);

    if (tierA)
        conv_kernel<<<5472, 256, 0, stream>>>(query, key, value, Wq, Wk, Wv, flags, Xbf, Wbf, 1);
    else if (tierB)
        conv_kernel<<<864, 256, 0, stream>>>(query, key, value, Wq, Wk, Wv, flags, Xbf, Wbf, 0);

    idx_kernel<<<dim3(16, 16, Bsz), 256, 0, stream>>>(tpos, flags, idxb);

    if (tierA)
        proj_kernel<<<dim3(64, 6, 3), 256, 0, stream>>>(
            Xbf, Xbf + NXz, Xbf + 2 * NXz,
            Wbf, bq, Wbf + NWz, bk, Wbf + 2 * NWz, bv,
            Qw, Kw, Vw, flags, 1, 1);
    else if (tierB)
        proj_kernel<<<dim3(64, 6, 3), 256, 0, stream>>>(
            query, key, value,
            Wbf, bq, Wbf + NWz, bk, Wbf + 2 * NWz, bv,
            Qw, Kw, Vw, flags, 0, 1);
    else
        proj_kernel<<<dim3(64, 6, 3), 256, 0, stream>>>(
            query, key, value, Wq, bq, Wk, bk, Wv, bv,
            Qw, Kw, Vw, flags, 0, 0);

    attn_kernel<<<dim3(16, Hn, Bsz), 256, 0, stream>>>(
        Qw, (const short*)Kw, (const short*)Vw, idxb, emb, d_out, flags);
}